// Round 3
// baseline (724.637 us; speedup 1.0000x reference)
//
#include <hip/hip_runtime.h>
#include <hip/hip_bf16.h>
#include <math.h>

// ---------------------------------------------------------------------------
// MultiDirectionalGridAttention. FP32 in/out; bf16 MFMA core, fp32 accum.
// B=4, T=1024 (32x32 grid), D=1024, NH=16, hd=64.
//
// R11 = R10 + attn latency attack:
//  - q-tile pairing (qt, 7-qt): every block = 18 k-tiles, grid (4,256) =
//    1024 uniform blocks = exactly 4/CU; XCD swizzle keeps all 4 q-blocks
//    of one (dir,b,h) on one XCD (K/V L2 reuse).
//  - K pre-scaled by 0.125 at the qkv epilogue (bit-exact pow2) -> no
//    per-tile scale muls in attn.
//  - causal mask applied only on boundary tiles (wave-uniform test).
//  - defer-rescale: skip alpha/exp + o-rescale when no new row max (__any).
//  - gemm_bt2: end-of-tile vmcnt(0) folded into phase-3 barrier (1 barrier
//    saved per K-tile).
//
// Batched ws (168 MB): [0,8)x_c->wout_c  [8,32)wq_c  [32,40)wo_c
//   [40,104) qk 4x16MB (pos-order [Q|K], ldc 2048) -> concat[40,72), wg[72,104)
//       -> part4 [40,104) (4x16MB, after gate)
//   [104,136) vt 4x8MB  [136,168) y->gated
// ---------------------------------------------------------------------------

typedef __bf16 bf16_t;
typedef __bf16 bf16x4 __attribute__((ext_vector_type(4)));
typedef __bf16 bf16x8 __attribute__((ext_vector_type(8)));
typedef float  f32x4  __attribute__((ext_vector_type(4)));

#define MFMA16(a, b, c) __builtin_amdgcn_mfma_f32_16x16x32_bf16((a), (b), (c), 0, 0, 0)

__device__ __forceinline__ void async16(const bf16_t* g, bf16_t* l) {
  __builtin_amdgcn_global_load_lds((const __attribute__((address_space(1))) void*)g,
                                   (__attribute__((address_space(3))) void*)l,
                                   16, 0, 0);
}

// 16-lane (DPP row) all-reduce: xor1, xor2 quad-perms then row_ror:4, row_ror:8.
__device__ __forceinline__ float dpp_max16(float x) {
  float t;
  t = __builtin_bit_cast(float, __builtin_amdgcn_update_dpp(0, __builtin_bit_cast(int, x), 0xB1, 0xF, 0xF, true));
  x = fmaxf(x, t);
  t = __builtin_bit_cast(float, __builtin_amdgcn_update_dpp(0, __builtin_bit_cast(int, x), 0x4E, 0xF, 0xF, true));
  x = fmaxf(x, t);
  t = __builtin_bit_cast(float, __builtin_amdgcn_update_dpp(0, __builtin_bit_cast(int, x), 0x124, 0xF, 0xF, true));
  x = fmaxf(x, t);
  t = __builtin_bit_cast(float, __builtin_amdgcn_update_dpp(0, __builtin_bit_cast(int, x), 0x128, 0xF, 0xF, true));
  x = fmaxf(x, t);
  return x;
}
__device__ __forceinline__ float dpp_sum16(float x) {
  float t;
  t = __builtin_bit_cast(float, __builtin_amdgcn_update_dpp(0, __builtin_bit_cast(int, x), 0xB1, 0xF, 0xF, true));
  x += t;
  t = __builtin_bit_cast(float, __builtin_amdgcn_update_dpp(0, __builtin_bit_cast(int, x), 0x4E, 0xF, 0xF, true));
  x += t;
  t = __builtin_bit_cast(float, __builtin_amdgcn_update_dpp(0, __builtin_bit_cast(int, x), 0x124, 0xF, 0xF, true));
  x += t;
  t = __builtin_bit_cast(float, __builtin_amdgcn_update_dpp(0, __builtin_bit_cast(int, x), 0x128, 0xF, 0xF, true));
  x += t;
  return x;
}

struct Ptr4 { const bf16_t* p[4]; };

// Causal-order position p <-> token t (involution).
__device__ __forceinline__ int perm_t(int p, int dir) {
  int q = (dir & 1) ? (1023 - p) : p;
  if (dir >= 2) q = ((q & 31) << 5) | (q >> 5);
  return q;
}

// ------------------- batched fp32 -> bf16 convert (<=9 segments) ------------
struct CvtDesc {
  const float* src[9];
  bf16_t* dst[9];
  int n8[9];
};

__device__ __forceinline__ void cvt8(const float* in, bf16_t* out, int i) {
  const float4 a = ((const float4*)in)[i * 2];
  const float4 b = ((const float4*)in)[i * 2 + 1];
  bf16x8 o;
  o[0] = (bf16_t)a.x; o[1] = (bf16_t)a.y; o[2] = (bf16_t)a.z; o[3] = (bf16_t)a.w;
  o[4] = (bf16_t)b.x; o[5] = (bf16_t)b.y; o[6] = (bf16_t)b.z; o[7] = (bf16_t)b.w;
  ((bf16x8*)out)[i] = o;
}

__global__ __launch_bounds__(256) void cvt9_k(CvtDesc d) {
  const int seg = blockIdx.y;
  const int i = blockIdx.x * 256 + threadIdx.x;
  if (i >= d.n8[seg]) return;
  cvt8(d.src[seg], d.dst[seg], i);
}

// ---------------------------------------------------------------------------
// gemm_bt2: C = A * B^T, bf16 in, fp32 acc. 256x256 tile, BK=64, 512 threads,
// 8 waves (2M x 4N), each wave owns 128x64 output (acc[8][4] f32x4).
// Double-buffered 128 KiB LDS; per K-tile 4 phases of
//   {ds_read frags ; stage half-tile ; s_barrier ; lgkmcnt(0) ;
//    setprio(1) ; 16 MFMA ; setprio(0) ; s_barrier}
// Prefetch loads for tile kt+1 issued in phases 0-1 of kt; the end-of-tile
// vmcnt(0) is folded into phase-3's trailing barrier. LDS rows 128B,
// 16B-block XOR swizzle blk' = blk ^ (row&7) (both-sides).
// MODE 0: bf16 C.  MODE 1: sigmoid-gate vs gin.  MODE 3: fp32 split-K part.
// MODE 4: qkv. K block (bn in [1024,2048)) pre-scaled by 0.125.
// ---------------------------------------------------------------------------
template <int MODE>
__global__ __launch_bounds__(512, 2) void gemm_bt2(
    const bf16_t* __restrict__ A, long sAz, int lda,
    Ptr4 B4, int ldb,
    void* __restrict__ Cv, long sCz, int ldc, int K, int koff,
    const float* __restrict__ bias,
    const bf16_t* __restrict__ gin,
    bf16_t* __restrict__ vtp, long sVz, int dirbase) {
  constexpr int BM = 256, BN = 256, BK = 64;
  (void)BM; (void)BN;
  __shared__ __align__(16) char smem[131072];

  const int z = blockIdx.z;
  const bf16_t* Ap = A + (long)z * sAz;
  const bf16_t* Bp = B4.p[z];
  const int tid = threadIdx.x;
  const int lane = tid & 63;
  const int wave = tid >> 6;
  const int l15 = lane & 15, qd = lane >> 4;
  const int wm = wave >> 2, wn = wave & 3;  // 2 x 4 wave grid
  const int bm = blockIdx.y * 256, bn = blockIdx.x * 256;
  const int kz = (MODE == 3) ? z * koff : 0;
  const int NT = K / BK;

  // ---- staging thread-constants (pre-swizzled global source) ----
  const int row0 = tid >> 3;                          // 0..63
  const int blkp = ((tid & 7) ^ (row0 & 7)) * 8;      // swizzled 16B block (elems)
  const bf16_t* gA = Ap + (long)(bm + row0) * lda + blkp + kz;
  const bf16_t* gB = Bp + (long)(bn + row0) * ldb + blkp + kz;
  char* const sm = (char*)smem;
  const int ldsT = tid * 16;                          // lane-linear dest

  // ---- fragment read bases (byte offsets inside one buffer) ----
  const int xorv = (l15 & 7) << 4;
  const int aBase = (wm * 128 + l15) * 128;           // A region [0, 32KB)
  const int bBase = 32768 + (wn * 64 + l15) * 128;    // B region [32KB, 64KB)
  const int colk0 = (qd * 16) ^ xorv;
  const int colk1 = (64 + qd * 16) ^ xorv;

  f32x4 acc[8][4];
#pragma unroll
  for (int i = 0; i < 8; i++)
#pragma unroll
    for (int j = 0; j < 4; j++) acc[i][j] = (f32x4){0.f, 0.f, 0.f, 0.f};

  // ---- prologue: stage tile 0 into buf 0 ----
#pragma unroll
  for (int u = 0; u < 4; u++)
    async16(gA + (long)(u * 64) * lda, (bf16_t*)(sm + u * 8192 + ldsT));
#pragma unroll
  for (int u = 0; u < 4; u++)
    async16(gB + (long)(u * 64) * ldb, (bf16_t*)(sm + 32768 + u * 8192 + ldsT));
  asm volatile("s_waitcnt vmcnt(0)" ::: "memory");
  __builtin_amdgcn_s_barrier();

  for (int kt = 0; kt < NT; ++kt) {
    const int c = kt & 1;
    const char* sa = sm + c * 65536;
    const int nb = (c ^ 1) * 65536;
    const long ko = (long)(kt + 1) * BK;
    bf16x8 bF[4][2];
#pragma unroll
    for (int p = 0; p < 4; ++p) {
      // -- ds-read this phase's fragments --
      if (p == 0) {
#pragma unroll
        for (int n = 0; n < 4; ++n) {
          bF[n][0] = *(const bf16x8*)(sa + bBase + n * 2048 + colk0);
          bF[n][1] = *(const bf16x8*)(sa + bBase + n * 2048 + colk1);
        }
      }
      bf16x8 aF[2][2];
#pragma unroll
      for (int mm = 0; mm < 2; ++mm) {
        aF[mm][0] = *(const bf16x8*)(sa + aBase + (p * 2 + mm) * 2048 + colk0);
        aF[mm][1] = *(const bf16x8*)(sa + aBase + (p * 2 + mm) * 2048 + colk1);
      }
      // -- stage next tile (A halves in phase 0, B halves in phase 1) --
      if (kt + 1 < NT) {
        if (p == 0) {
#pragma unroll
          for (int u = 0; u < 4; u++)
            async16(gA + (long)(u * 64) * lda + ko,
                    (bf16_t*)(sm + nb + u * 8192 + ldsT));
        } else if (p == 1) {
#pragma unroll
          for (int u = 0; u < 4; u++)
            async16(gB + (long)(u * 64) * ldb + ko,
                    (bf16_t*)(sm + nb + 32768 + u * 8192 + ldsT));
        }
      }
      __builtin_amdgcn_s_barrier();
      asm volatile("s_waitcnt lgkmcnt(0)" ::: "memory");
      __builtin_amdgcn_s_setprio(1);
#pragma unroll
      for (int kh = 0; kh < 2; ++kh)
#pragma unroll
        for (int mm = 0; mm < 2; ++mm)
#pragma unroll
          for (int n = 0; n < 4; ++n)
            acc[p * 2 + mm][n] =
                MFMA16(aF[mm][kh], bF[n][kh], acc[p * 2 + mm][n]);
      __builtin_amdgcn_s_setprio(0);
      if (p == 3 && kt + 1 < NT)  // next tile resident before its phase-0 reads
        asm volatile("s_waitcnt vmcnt(0)" ::: "memory");
      __builtin_amdgcn_s_barrier();
    }
  }

  // ---- epilogue: 4 passes of 64 rows through fp32 LDS bounce (overlay) ----
  if constexpr (MODE == 4) {
    const int dir = dirbase + z;
    if (bn < 2048) {  // Q,K: MODE-0-style bounce, row-permuted coalesced store
      bf16_t* qkz = (bf16_t*)Cv + (long)z * sCz;
      const float ksc = (bn >= 1024) ? 0.125f : 1.0f;  // pre-scale K by 1/8
      float* sC = (float*)smem;
#pragma unroll
      for (int p = 0; p < 4; ++p) {
        if (p) __syncthreads();
        if (wm == (p >> 1)) {
#pragma unroll
          for (int mm = 0; mm < 4; ++mm) {
            const int m = (p & 1) * 4 + mm;
#pragma unroll
            for (int n = 0; n < 4; ++n)
#pragma unroll
              for (int r = 0; r < 4; ++r)
                sC[(mm * 16 + qd * 4 + r) * 260 + wn * 64 + n * 16 + l15] =
                    acc[m][n][r];
          }
        }
        __syncthreads();
#pragma unroll
        for (int i = 0; i < 8; ++i) {
          const int idx = i * 512 + tid;
          const int rl = idx >> 6, c4 = (idx & 63) * 4;
          const float4 v4 = *(const float4*)&sC[rl * 260 + c4];
          const int grow = bm + p * 64 + rl;
          const int prow = (grow & ~1023) | perm_t(grow & 1023, dir);
          bf16x4 o;
          o[0] = (bf16_t)(v4.x * ksc); o[1] = (bf16_t)(v4.y * ksc);
          o[2] = (bf16_t)(v4.z * ksc); o[3] = (bf16_t)(v4.w * ksc);
          *(bf16x4*)(qkz + (long)prow * ldc + bn + c4) = o;
        }
      }
    } else {  // V: transposed bounce sCt[256 cols][68], pos-major stores
      bf16_t* vz = vtp + (long)z * sVz;
      float* sCt = (float*)smem;
#pragma unroll
      for (int p = 0; p < 4; ++p) {
        if (p) __syncthreads();
        if (wm == (p >> 1)) {
#pragma unroll
          for (int mm = 0; mm < 4; ++mm) {
            const int m = (p & 1) * 4 + mm;
#pragma unroll
            for (int n = 0; n < 4; ++n)
#pragma unroll
              for (int r = 0; r < 4; ++r)
                sCt[(wn * 64 + n * 16 + l15) * 68 + mm * 16 + qd * 4 + r] =
                    acc[m][n][r];
          }
        }
        __syncthreads();
#pragma unroll
        for (int i = 0; i < 8; ++i) {
          const int idx = i * 512 + tid;         // 4096 = 256 cols x 16 chunks
          const int col = idx >> 4, tq = idx & 15;
          const float4 v4 = *(const float4*)&sCt[col * 68 + tq * 4];
          const int t0 = (bm & 1023) + p * 64 + tq * 4;
          const int bb = bm >> 10;
          const int ch = bn + col - 2048;
          bf16_t* vrow =
              vz + (((long)bb * 16 + (ch >> 6)) * 64 + (ch & 63)) * 1024;
          if (dir == 0) {
            bf16x4 o;
            o[0] = (bf16_t)v4.x; o[1] = (bf16_t)v4.y;
            o[2] = (bf16_t)v4.z; o[3] = (bf16_t)v4.w;
            *(bf16x4*)(vrow + t0) = o;
          } else if (dir == 1) {
            bf16x4 o;
            o[0] = (bf16_t)v4.w; o[1] = (bf16_t)v4.z;
            o[2] = (bf16_t)v4.y; o[3] = (bf16_t)v4.x;
            *(bf16x4*)(vrow + (1020 - t0)) = o;
          } else {
            vrow[perm_t(t0 + 0, dir)] = (bf16_t)v4.x;
            vrow[perm_t(t0 + 1, dir)] = (bf16_t)v4.y;
            vrow[perm_t(t0 + 2, dir)] = (bf16_t)v4.z;
            vrow[perm_t(t0 + 3, dir)] = (bf16_t)v4.w;
          }
        }
      }
    }
  } else {
    float* sC = (float*)smem;
#pragma unroll
    for (int p = 0; p < 4; ++p) {
      if (p) __syncthreads();
      if (wm == (p >> 1)) {
#pragma unroll
        for (int mm = 0; mm < 4; ++mm) {
          const int m = (p & 1) * 4 + mm;
#pragma unroll
          for (int n = 0; n < 4; ++n)
#pragma unroll
            for (int r = 0; r < 4; ++r)
              sC[(mm * 16 + qd * 4 + r) * 260 + wn * 64 + n * 16 + l15] =
                  acc[m][n][r];
        }
      }
      __syncthreads();
#pragma unroll
      for (int i = 0; i < 8; ++i) {
        const int idx = i * 512 + tid;
        const int rl = idx >> 6, c4 = (idx & 63) * 4;
        const float4 v4 = *(const float4*)&sC[rl * 260 + c4];
        const int grow = bm + p * 64 + rl;
        const int gcol = bn + c4;
        const long goff = (long)grow * ldc + gcol;
        if constexpr (MODE == 0) {
          bf16x4 o;
          o[0] = (bf16_t)v4.x; o[1] = (bf16_t)v4.y;
          o[2] = (bf16_t)v4.z; o[3] = (bf16_t)v4.w;
          *(bf16x4*)((bf16_t*)Cv + (long)z * sCz + goff) = o;
        } else if constexpr (MODE == 1) {
          const float4 bb = *(const float4*)&bias[gcol];
          const bf16x4 gv = *(const bf16x4*)&gin[goff];
          bf16x4 o;
          o[0] = (bf16_t)((float)gv[0] / (1.f + __expf(-(v4.x + bb.x))));
          o[1] = (bf16_t)((float)gv[1] / (1.f + __expf(-(v4.y + bb.y))));
          o[2] = (bf16_t)((float)gv[2] / (1.f + __expf(-(v4.z + bb.z))));
          o[3] = (bf16_t)((float)gv[3] / (1.f + __expf(-(v4.w + bb.w))));
          *(bf16x4*)((bf16_t*)Cv + goff) = o;
        } else {
          *(float4*)((float*)Cv + (long)z * sCz + goff) = v4;
        }
      }
    }
  }
}

// ---------------------------------------------------------------------------
// Legacy 128x128 gemm (m97 structure) — retained for the low-ws fallback path.
// ---------------------------------------------------------------------------
template <int MODE>
__global__ __launch_bounds__(256) void gemm_bt(
    const bf16_t* __restrict__ A, long sAz, int lda,
    Ptr4 B4, int ldb,
    void* __restrict__ Cv, long sCz, int ldc, int K, int koff,
    const float* __restrict__ bias,
    const bf16_t* __restrict__ gin,
    bf16_t* __restrict__ vtp, long sVz, int dirbase) {
  constexpr int BM = 128, BN = 128, BK = 32;
  __shared__ __align__(16) char smem[18432];
  bf16_t* sA = (bf16_t*)smem;
  bf16_t* sB = (bf16_t*)(smem + BM * BK * 2);
  float* sC = (float*)smem;

  const int z = blockIdx.z;
  const bf16_t* Ap = A + (long)z * sAz;
  const bf16_t* Bp = B4.p[z];
  const int tid = threadIdx.x;
  const int wave = tid >> 6, lane = tid & 63;
  const int lane15 = lane & 15, quad = lane >> 4;
  const int bm = blockIdx.y * BM, bn = blockIdx.x * BN;
  const int wm = (wave >> 1) * 64, wn = (wave & 1) * 64;

  f32x4 acc[4][4];
#pragma unroll
  for (int i = 0; i < 4; i++)
#pragma unroll
    for (int j = 0; j < 4; j++) acc[i][j] = (f32x4){0.f, 0.f, 0.f, 0.f};

  const int srow = wave * 16 + (lane >> 2);
  const int skoff = (lane & 3) * 8;
  const int kz = (MODE == 3) ? z * koff : 0;
  const bf16_t* ga = Ap + (long)(bm + srow) * lda + skoff + kz;
  const bf16_t* gb = Bp + (long)(bn + srow) * ldb + skoff + kz;
  bf16_t* la = &sA[srow * BK + skoff];
  bf16_t* lb = &sB[srow * BK + skoff];

  for (int k0 = 0; k0 < K; k0 += BK) {
    __syncthreads();
    async16(ga + k0, la);
    async16(ga + k0 + (long)64 * lda, la + 64 * BK);
    async16(gb + k0, lb);
    async16(gb + k0 + (long)64 * ldb, lb + 64 * BK);
    __syncthreads();

    bf16x8 af[4], bfv[4];
#pragma unroll
    for (int i = 0; i < 4; i++)
      af[i] = *(const bf16x8*)&sA[(wm + i * 16 + lane15) * BK + quad * 8];
#pragma unroll
    for (int j = 0; j < 4; j++)
      bfv[j] = *(const bf16x8*)&sB[(wn + j * 16 + lane15) * BK + quad * 8];
#pragma unroll
    for (int i = 0; i < 4; i++)
#pragma unroll
      for (int j = 0; j < 4; j++)
        acc[i][j] = MFMA16(af[i], bfv[j], acc[i][j]);
  }

  __syncthreads();  // all waves done reading sA/sB before the sC overlay

  // ------------- epilogue -------------
  if constexpr (MODE == 4) {
    const int dir = dirbase + z;
    if (bn < 2048) {  // Q,K: 4 passes of 16+16 rows, row-permuted store
      bf16_t* qkz = (bf16_t*)Cv + (long)z * sCz;
      const float ksc = (bn >= 1024) ? 0.125f : 1.0f;  // pre-scale K by 1/8
#pragma unroll
      for (int p = 0; p < 4; p++) {
        if (p) __syncthreads();
        const int sr = (wm >> 2) + quad * 4;  // wm=0 -> 0..15, wm=64 -> 16..31
#pragma unroll
        for (int r = 0; r < 4; r++)
#pragma unroll
          for (int j = 0; j < 4; j++)
            sC[(sr + r) * 144 + wn + j * 16 + lane15] = acc[p][j][r];
        __syncthreads();
#pragma unroll
        for (int c = 0; c < 4; c++) {
          const int idx = c * 256 + tid;
          const int srr = idx >> 5, chunk = idx & 31;
          const float4 v4 = *(const float4*)&sC[srr * 144 + chunk * 4];
          const int grow = bm + p * 16 + (srr & 15) + (srr >> 4) * 64;
          const int prow = (grow & ~1023) | perm_t(grow & 1023, dir);
          bf16x4 o;
          o[0] = (bf16_t)(v4.x * ksc); o[1] = (bf16_t)(v4.y * ksc);
          o[2] = (bf16_t)(v4.z * ksc); o[3] = (bf16_t)(v4.w * ksc);
          *(bf16x4*)(qkz + (long)prow * 2048 + bn + chunk * 4) = o;
        }
      }
    } else {  // V: 4 passes (row-half p x col-half q) -> vt[b][h][d][pos]
      bf16_t* vz = vtp + (long)z * sVz;
      float* sCt = sC;  // [col 0..63][tok-compressed 0..63], stride 68
#pragma unroll
      for (int p = 0; p < 2; p++)
#pragma unroll
        for (int q = 0; q < 2; q++) {
          if (p || q) __syncthreads();
          if ((wave & 1) == q) {  // only waves with wn == 64q hold these cols
#pragma unroll
            for (int ii = 0; ii < 2; ii++) {
              const int i = 2 * p + ii;
              const int srb = (wm >> 1) + ii * 16 + quad * 4;
#pragma unroll
              for (int r = 0; r < 4; r++)
#pragma unroll
                for (int j = 0; j < 4; j++)
                  sCt[(j * 16 + lane15) * 68 + srb + r] = acc[i][j][r];
            }
          }
          __syncthreads();
#pragma unroll
          for (int c = 0; c < 4; c++) {
            const int idx = c * 256 + tid;
            const int col = idx >> 4, tq = idx & 15;
            const int srr0 = (tq & 7) * 4 + (tq >> 3) * 32;
            const float4 v4 = *(const float4*)&sCt[col * 68 + srr0];
            const int t0 = (bm & 1023) + p * 32 + (srr0 & 31) + (srr0 >> 5) * 64;
            const int bb = bm >> 10;
            const int ch = bn + 64 * q + col - 2048;
            bf16_t* vrow =
                vz + (((long)bb * 16 + (ch >> 6)) * 64 + (ch & 63)) * 1024;
            if (dir == 0) {
              bf16x4 o;
              o[0] = (bf16_t)v4.x; o[1] = (bf16_t)v4.y;
              o[2] = (bf16_t)v4.z; o[3] = (bf16_t)v4.w;
              *(bf16x4*)(vrow + t0) = o;
            } else if (dir == 1) {
              bf16x4 o;
              o[0] = (bf16_t)v4.w; o[1] = (bf16_t)v4.z;
              o[2] = (bf16_t)v4.y; o[3] = (bf16_t)v4.x;
              *(bf16x4*)(vrow + (1020 - t0)) = o;
            } else {
              vrow[perm_t(t0 + 0, dir)] = (bf16_t)v4.x;
              vrow[perm_t(t0 + 1, dir)] = (bf16_t)v4.y;
              vrow[perm_t(t0 + 2, dir)] = (bf16_t)v4.z;
              vrow[perm_t(t0 + 3, dir)] = (bf16_t)v4.w;
            }
          }
        }
    }
  } else {
#pragma unroll
    for (int p = 0; p < 4; p++) {
      if (p) __syncthreads();
      const int sr = (wm >> 2) + quad * 4;
#pragma unroll
      for (int r = 0; r < 4; r++)
#pragma unroll
        for (int j = 0; j < 4; j++)
          sC[(sr + r) * 144 + wn + j * 16 + lane15] = acc[p][j][r];
      __syncthreads();
#pragma unroll
      for (int c = 0; c < 4; c++) {
        const int idx = c * 256 + tid;
        const int srr = idx >> 5, chunk = idx & 31;
        const float4 v4 = *(const float4*)&sC[srr * 144 + chunk * 4];
        const int grow = bm + p * 16 + (srr & 15) + (srr >> 4) * 64;
        const int gcol = bn + chunk * 4;
        const long goff = (long)grow * ldc + gcol;
        if constexpr (MODE == 0) {
          bf16x4 o;
          o[0] = (bf16_t)v4.x; o[1] = (bf16_t)v4.y;
          o[2] = (bf16_t)v4.z; o[3] = (bf16_t)v4.w;
          *(bf16x4*)((bf16_t*)Cv + (long)z * sCz + goff) = o;
        } else if constexpr (MODE == 1) {
          const float4 bb = *(const float4*)&bias[gcol];
          const bf16x4 gv = *(const bf16x4*)&gin[goff];
          bf16x4 o;
          o[0] = (bf16_t)((float)gv[0] / (1.f + __expf(-(v4.x + bb.x))));
          o[1] = (bf16_t)((float)gv[1] / (1.f + __expf(-(v4.y + bb.y))));
          o[2] = (bf16_t)((float)gv[2] / (1.f + __expf(-(v4.z + bb.z))));
          o[3] = (bf16_t)((float)gv[3] / (1.f + __expf(-(v4.w + bb.w))));
          *(bf16x4*)((bf16_t*)Cv + goff) = o;
        } else {
          *(float4*)((float*)Cv + (long)z * sCz + goff) = v4;
        }
      }
    }
  }
}

// ---------------------------------------------------------------------------
// Flash attention, pure-causal in position space (no perm in hot loop).
// Block = 4 waves x 32 q-rows; each block runs TWO q-tiles (7-bx, then bx)
// -> uniform 18 k-tiles/block; grid (4, Ybh): XCD-swizzled so all 4 q-blocks
// of one (dir,b,h) share an XCD. K comes pre-scaled by 0.125 from qkv.
// Causal mask only on boundary tiles; defer-rescale when no new row max.
// ---------------------------------------------------------------------------
__global__ __launch_bounds__(256, 4) void attn_k(
    const bf16_t* __restrict__ qk, long sQz,
    const bf16_t* __restrict__ vt, long sVz,
    bf16_t* __restrict__ y, long sYz, int dir0) {
  // XCD swizzle: physical p0 round-robins XCDs; give each XCD a contiguous
  // chunk of bh so the 4 q-blocks of each (dir,b,h) land on one XCD.
  const int p0 = blockIdx.y * 4 + blockIdx.x;
  const int chunk = gridDim.y >> 1;              // (gy*4)/8
  const int lg = (p0 & 7) * chunk + (p0 >> 3);
  const int bx = lg & 3, by = lg >> 2;
  const int zi = by >> 6;
  const int bh = by & 63;
  const int dir = dir0 + zi;
  const int b = bh >> 4, h = bh & 15;
  const int tid = threadIdx.x;
  const int wave = tid >> 6, lane = tid & 63;
  const int lane15 = lane & 15, quad = lane >> 4;
  const int hoff = h * 64;
  const bf16_t* base = qk + (long)zi * sQz + (long)b * 1024 * 2048;
  const bf16_t* vth = vt + (long)zi * sVz + ((long)b * 16 + h) * 64 * 1024;
  bf16_t* yd = y + (long)zi * sYz;

  __shared__ __align__(16) bf16_t sK[64 * 72];
  __shared__ __align__(16) bf16_t sVt[64 * 72];
  __shared__ __align__(16) bf16_t sP[4][32 * 72];

  const int krow = tid >> 3, kd = (tid & 7) * 8;   // K: 32 rows x 128B per pass
  const int vd = tid >> 2, pc = (tid & 3) * 8;     // V: 64 d-rows x 64B per pass
  const bf16_t* kb_g = base + 1024 + hoff;
  const float FNEG = -1e30f;

  for (int pass = 0; pass < 2; ++pass) {
    const int qt = pass ? bx : 7 - bx;   // heavy tile first

    // Q fragments: 2 row-groups of 16, A-layout (m=lane15, k=quad*8+j)
    bf16x8 qa[2][2];
#pragma unroll
    for (int g = 0; g < 2; g++) {
      const int row = qt * 128 + wave * 32 + g * 16 + lane15;
      qa[g][0] = *(const bf16x8*)(base + (long)row * 2048 + hoff + quad * 8);
      qa[g][1] = *(const bf16x8*)(base + (long)row * 2048 + hoff + 32 + quad * 8);
    }

    float mrow[2][4], lrow[2][4];
    f32x4 o[2][4];
#pragma unroll
    for (int g = 0; g < 2; g++)
#pragma unroll
      for (int r = 0; r < 4; r++) { mrow[g][r] = FNEG; lrow[g][r] = 0.f; }
#pragma unroll
    for (int g = 0; g < 2; g++)
#pragma unroll
      for (int d4 = 0; d4 < 4; d4++) o[g][d4] = (f32x4){0.f, 0.f, 0.f, 0.f};

    // preload tile 0
    bf16x8 kA = *(const bf16x8*)(kb_g + (long)krow * 2048 + kd);
    bf16x8 kB = *(const bf16x8*)(kb_g + (long)(32 + krow) * 2048 + kd);
    bf16x8 vA = *(const bf16x8*)(vth + (long)vd * 1024 + pc);
    bf16x8 vB = *(const bf16x8*)(vth + (long)vd * 1024 + 32 + pc);

    const int qlo = qt * 128 + wave * 32;        // wave's lowest q-row
    const int ktiles = 2 * qt + 2;
    for (int kt = 0; kt < ktiles; kt++) {
      __syncthreads();  // prev tile's LDS reads done
      *(bf16x8*)&sK[krow * 72 + kd] = kA;
      *(bf16x8*)&sK[(krow + 32) * 72 + kd] = kB;
      *(bf16x8*)&sVt[vd * 72 + pc] = vA;
      *(bf16x8*)&sVt[vd * 72 + 32 + pc] = vB;
      __syncthreads();  // staging visible
      if (kt + 1 < ktiles) {  // prefetch next tile into regs (overlaps compute)
        const int nb = (kt + 1) * 64;
        kA = *(const bf16x8*)(kb_g + (long)(nb + krow) * 2048 + kd);
        kB = *(const bf16x8*)(kb_g + (long)(nb + 32 + krow) * 2048 + kd);
        vA = *(const bf16x8*)(vth + (long)vd * 1024 + nb + pc);
        vB = *(const bf16x8*)(vth + (long)vd * 1024 + nb + 32 + pc);
      }
      const int kbase = kt * 64;

      // S = Q K^T (K pre-scaled): per g, 4 key-groups x 2 k-chunks
      bf16x8 kb[4][2];
#pragma unroll
      for (int ns = 0; ns < 4; ns++) {
        kb[ns][0] = *(const bf16x8*)&sK[(ns * 16 + lane15) * 72 + quad * 8];
        kb[ns][1] = *(const bf16x8*)&sK[(ns * 16 + lane15) * 72 + 32 + quad * 8];
      }
      f32x4 s[2][4];
#pragma unroll
      for (int g = 0; g < 2; g++)
#pragma unroll
        for (int ns = 0; ns < 4; ns++) {
          f32x4 t = (f32x4){0.f, 0.f, 0.f, 0.f};
          t = MFMA16(qa[g][0], kb[ns][0], t);
          t = MFMA16(qa[g][1], kb[ns][1], t);
          s[g][ns] = t;
        }
      // causal mask (boundary tiles only; wave-uniform test)
      if (kbase + 63 > qlo) {
#pragma unroll
        for (int g = 0; g < 2; g++) {
          const int qc = qlo + g * 16 + quad * 4;
#pragma unroll
          for (int ns = 0; ns < 4; ns++) {
            const int kp = kbase + ns * 16 + lane15;
#pragma unroll
            for (int r = 0; r < 4; r++)
              if (kp > qc + r) s[g][ns][r] = FNEG;
          }
        }
      }
      // online softmax: tile max, defer-rescale if no new max
      float tm[2][4];
#pragma unroll
      for (int g = 0; g < 2; g++)
#pragma unroll
        for (int r = 0; r < 4; r++) {
          float t = fmaxf(fmaxf(s[g][0][r], s[g][1][r]),
                          fmaxf(s[g][2][r], s[g][3][r]));
          tm[g][r] = dpp_max16(t);
        }
      bool up = false;
#pragma unroll
      for (int g = 0; g < 2; g++)
#pragma unroll
        for (int r = 0; r < 4; r++) up = up || (tm[g][r] > mrow[g][r]);
      if (__any(up)) {
#pragma unroll
        for (int g = 0; g < 2; g++) {
          float alpha[4];
#pragma unroll
          for (int r = 0; r < 4; r++) {
            const float mn = fmaxf(mrow[g][r], tm[g][r]);
            alpha[r] = __expf(mrow[g][r] - mn);
            mrow[g][r] = mn;
          }
#pragma unroll
          for (int r = 0; r < 4; r++) lrow[g][r] *= alpha[r];
#pragma unroll
          for (int d4 = 0; d4 < 4; d4++)
#pragma unroll
            for (int r = 0; r < 4; r++) o[g][d4][r] *= alpha[r];
        }
      }
#pragma unroll
      for (int g = 0; g < 2; g++) {
#pragma unroll
        for (int ns = 0; ns < 4; ns++)
#pragma unroll
          for (int r = 0; r < 4; r++)
            s[g][ns][r] = __expf(s[g][ns][r] - mrow[g][r]);
#pragma unroll
        for (int r = 0; r < 4; r++) {
          float ts = (s[g][0][r] + s[g][1][r]) + (s[g][2][r] + s[g][3][r]);
          lrow[g][r] += dpp_sum16(ts);
        }
        // P: C-layout -> bf16 A-layout via per-wave LDS scratch
#pragma unroll
        for (int ns = 0; ns < 4; ns++)
#pragma unroll
          for (int r = 0; r < 4; r++)
            sP[wave][(g * 16 + quad * 4 + r) * 72 + ns * 16 + lane15] =
                (bf16_t)s[g][ns][r];
      }
      // PV
      bf16x8 vb[4][2];
#pragma unroll
      for (int d4 = 0; d4 < 4; d4++) {
        vb[d4][0] = *(const bf16x8*)&sVt[(d4 * 16 + lane15) * 72 + quad * 8];
        vb[d4][1] = *(const bf16x8*)&sVt[(d4 * 16 + lane15) * 72 + 32 + quad * 8];
      }
#pragma unroll
      for (int g = 0; g < 2; g++) {
        const bf16x8 pa0 = *(const bf16x8*)&sP[wave][(g * 16 + lane15) * 72 + quad * 8];
        const bf16x8 pa1 = *(const bf16x8*)&sP[wave][(g * 16 + lane15) * 72 + 32 + quad * 8];
#pragma unroll
        for (int d4 = 0; d4 < 4; d4++) {
          o[g][d4] = MFMA16(pa0, vb[d4][0], o[g][d4]);
          o[g][d4] = MFMA16(pa1, vb[d4][1], o[g][d4]);
        }
      }
    }

    // epilogue: normalize, bounce through sP (per-wave), vector store + perm
#pragma unroll
    for (int g = 0; g < 2; g++)
#pragma unroll
      for (int r = 0; r < 4; r++) {
        const float rinv = 1.f / fmaxf(lrow[g][r], 1e-20f);
#pragma unroll
        for (int d4 = 0; d4 < 4; d4++)
          sP[wave][(g * 16 + quad * 4 + r) * 72 + d4 * 16 + lane15] =
              (bf16_t)(o[g][d4][r] * rinv);
      }
#pragma unroll
    for (int g = 0; g < 2; g++) {
      const bf16x8 o0 = *(const bf16x8*)&sP[wave][(g * 16 + lane15) * 72 + quad * 16];
      const bf16x8 o1 = *(const bf16x8*)&sP[wave][(g * 16 + lane15) * 72 + quad * 16 + 8];
      const int tok = perm_t(qt * 128 + wave * 32 + g * 16 + lane15, dir);
      bf16_t* yr = yd + ((long)b * 1024 + tok) * 1024 + hoff + quad * 16;
      *(bf16x8*)yr = o0;
      *(bf16x8*)(yr + 8) = o1;
    }
  }
}

// ---------------------------------------------------------------------------
// RMSNorm over rows of 1024: v = P0 + P1 (+ P2 + P3) + x (split-K reduce +
// residual). p2/p3 may be null (2-way split fallback).
// ---------------------------------------------------------------------------
__global__ __launch_bounds__(256) void rmsnorm_k(const float* __restrict__ p0,
                                                 const float* __restrict__ p1,
                                                 const float* __restrict__ p2,
                                                 const float* __restrict__ p3,
                                                 const float* __restrict__ x,
                                                 const float* __restrict__ w,
                                                 float* __restrict__ out) {
  const int row = blockIdx.x, tid = threadIdx.x;
  const long off = (long)row * 1024;
  const float4 a = ((const float4*)(p0 + off))[tid];
  const float4 bq = ((const float4*)(p1 + off))[tid];
  const float4 c = ((const float4*)(x + off))[tid];
  float4 v;
  v.x = a.x + bq.x + c.x;
  v.y = a.y + bq.y + c.y;
  v.z = a.z + bq.z + c.z;
  v.w = a.w + bq.w + c.w;
  if (p2) {
    const float4 d = ((const float4*)(p2 + off))[tid];
    const float4 e = ((const float4*)(p3 + off))[tid];
    v.x += d.x + e.x;
    v.y += d.y + e.y;
    v.z += d.z + e.z;
    v.w += d.w + e.w;
  }
  float ss = v.x * v.x + v.y * v.y + v.z * v.z + v.w * v.w;
#pragma unroll
  for (int o2 = 32; o2 >= 1; o2 >>= 1) ss += __shfl_xor(ss, o2);
  __shared__ float wsum[4];
  if ((tid & 63) == 0) wsum[tid >> 6] = ss;
  __syncthreads();
  const float tot = wsum[0] + wsum[1] + wsum[2] + wsum[3];
  const float norm = rsqrtf(tot * (1.f / 1024.f) + 1e-6f);
  const float4 wv = ((const float4*)w)[tid];
  v.x = v.x * norm * wv.x;
  v.y = v.y * norm * wv.y;
  v.z = v.z * norm * wv.z;
  v.w = v.w * norm * wv.w;
  ((float4*)(out + off))[tid] = v;
}

// ---------------------------------------------------------------------------
extern "C" void kernel_launch(void* const* d_in, const int* in_sizes, int n_in,
                              void* d_out, int out_size, void* d_ws, size_t ws_size,
                              hipStream_t stream) {
  (void)in_sizes; (void)n_in; (void)out_size;
  const float* xf = (const float*)d_in[0];
  const float* wqkv_f[4] = {(const float*)d_in[1], (const float*)d_in[3],
                            (const float*)d_in[5], (const float*)d_in[7]};
  const float* wo_f[4] = {(const float*)d_in[2], (const float*)d_in[4],
                          (const float*)d_in[6], (const float*)d_in[8]};
  const float* wgate_f = (const float*)d_in[9];
  const float* bgate_f = (const float*)d_in[10];
  const float* wout_f = (const float*)d_in[11];
  const float* normw_f = (const float*)d_in[12];

  const long MB = 1l << 20;
  char* ws = (char*)d_ws;
  const dim3 blk(256);
  const dim3 blk2(512);
  const bool batched = ws_size >= (size_t)(168 * MB);
  const long sQK = 4096l * 2048;   // qk per-dir elems (16 MB)
  const long sVT = 4096l * 1024;   // vt per-dir elems (8 MB)
  const long sY  = 4096l * 1024;   // y per-dir elems (8 MB)

  if (batched) {
    bf16_t* x_c    = (bf16_t*)(ws);              // 8 MB   -> wout_c later
    bf16_t* wq_c   = (bf16_t*)(ws + 8 * MB);     // 24 MB
    bf16_t* wo_c   = (bf16_t*)(ws + 32 * MB);    // 8 MB
    bf16_t* qk     = (bf16_t*)(ws + 40 * MB);    // 64 MB (4 dirs, pos order)
    bf16_t* vt     = (bf16_t*)(ws + 104 * MB);   // 32 MB (4 dirs, [b][h][d][p])
    bf16_t* y      = (bf16_t*)(ws + 136 * MB);   // 32 MB -> gated
    bf16_t* concat = (bf16_t*)(ws + 40 * MB);    // 32 MB (phase 2, qk dirs 0-1 dead)
    bf16_t* wg_c   = (bf16_t*)(ws + 72 * MB);    // 32 MB (qk dirs 2-3 dead)
    bf16_t* wout_c = (bf16_t*)(ws);              // 8 MB (x dead)
    float*  part4  = (float*)(ws + 40 * MB);     // 64 MB (concat+wg dead after gate)
    bf16_t* gated  = y;

    {  // convert x, wqkv x4, wo x4
      CvtDesc cd;
      cd.src[0] = xf; cd.dst[0] = x_c; cd.n8[0] = 4194304 / 8;
      for (int d = 0; d < 4; d++) {
        cd.src[1 + d] = wqkv_f[d];
        cd.dst[1 + d] = wq_c + (long)d * 3145728;
        cd.n8[1 + d] = 3145728 / 8;
        cd.src[5 + d] = wo_f[d];
        cd.dst[5 + d] = wo_c + (long)d * 1048576;
        cd.n8[5 + d] = 1048576 / 8;
      }
      cvt9_k<<<dim3(2048, 9), blk, 0, stream>>>(cd);
    }
    {  // qkv GEMM (256^2 8-phase), 4 dirs: Q,K -> pos order; V -> vt transposed
      Ptr4 bq{{wq_c, wq_c + 3145728, wq_c + 2l * 3145728, wq_c + 3l * 3145728}};
      gemm_bt2<4><<<dim3(12, 16, 4), blk2, 0, stream>>>(
          x_c, 0, 1024, bq, 1024, qk, sQK, 2048, 1024, 0, nullptr, nullptr,
          vt, sVT, 0);
    }
    attn_k<<<dim3(4, 256), blk, 0, stream>>>(qk, sQK, vt, sVT, y, sY, 0);
    {  // convert wgate + wout (after attn: overlays qk/x space)
      CvtDesc cd;
      for (int s = 0; s < 9; s++) cd.n8[s] = 0;
      cd.src[0] = wgate_f; cd.dst[0] = wg_c; cd.n8[0] = 16777216 / 8;
      cd.src[1] = wout_f; cd.dst[1] = wout_c; cd.n8[1] = 4194304 / 8;
      cvt9_k<<<dim3(8192, 2), blk, 0, stream>>>(cd);
    }
    {  // out-proj, z-batched -> concat[:, z*1024:(z+1)*1024]  (256^2 8-phase)
      Ptr4 b4{{wo_c, wo_c + 1048576, wo_c + 2097152, wo_c + 3145728}};
      gemm_bt2<0><<<dim3(4, 16, 4), blk2, 0, stream>>>(
          y, sY, 1024, b4, 1024, concat, 1024, 4096, 1024, 0, nullptr, nullptr,
          nullptr, 0, 0);
    }
    {  // gated = sigmoid(concat@wg^T + b) * concat  (256^2 8-phase)
      Ptr4 b4{{wg_c, wg_c, wg_c, wg_c}};
      gemm_bt2<1><<<dim3(16, 16, 1), blk2, 0, stream>>>(
          concat, 0, 4096, b4, 4096, gated, 0, 4096, 4096, 0, bgate_f, concat,
          nullptr, 0, 0);
    }
    {  // split-K=4 w_out partials into part4 (concat/wg region, now dead)
      Ptr4 b4{{wout_c, wout_c, wout_c, wout_c}};
      gemm_bt2<3><<<dim3(4, 16, 4), blk2, 0, stream>>>(
          gated, 0, 4096, b4, 4096, part4, (long)4096 * 1024, 1024, 1024, 1024,
          nullptr, nullptr, nullptr, 0, 0);
    }
    rmsnorm_k<<<dim3(4096), blk, 0, stream>>>(
        part4, part4 + (long)4096 * 1024, part4 + 2l * 4096 * 1024,
        part4 + 3l * 4096 * 1024, xf, normw_f, (float*)d_out);
  } else {
    // fallback (96 MB): per-dir qkv+attn, legacy 128^2 GEMMs
    bf16_t* x_c    = (bf16_t*)(ws);              // 8 MB
    bf16_t* wq_c   = (bf16_t*)(ws + 8 * MB);     // 24 MB
    bf16_t* qk_d   = (bf16_t*)(ws + 32 * MB);    // 16 MB (per-dir)
    bf16_t* vt_d   = (bf16_t*)(ws + 48 * MB);    // 8 MB (per-dir)
    bf16_t* wo_c   = (bf16_t*)(ws + 56 * MB);    // 8 MB
    bf16_t* y      = (bf16_t*)(ws + 64 * MB);    // 32 MB -> gated
    bf16_t* concat = (bf16_t*)(ws);              // 32 MB (phase 2)
    bf16_t* wg_c   = (bf16_t*)(ws + 32 * MB);    // 32 MB (after out-proj)
    bf16_t* wout_c = (bf16_t*)(ws);              // 8 MB (after gate)
    float*  part   = (float*)(ws + 8 * MB);      // 32 MB
    bf16_t* gated  = y;

    {
      CvtDesc cd;
      cd.src[0] = xf; cd.dst[0] = x_c; cd.n8[0] = 4194304 / 8;
      for (int d = 0; d < 4; d++) {
        cd.src[1 + d] = wqkv_f[d];
        cd.dst[1 + d] = wq_c + (long)d * 3145728;
        cd.n8[1 + d] = 3145728 / 8;
        cd.src[5 + d] = wo_f[d];
        cd.dst[5 + d] = wo_c + (long)d * 1048576;
        cd.n8[5 + d] = 1048576 / 8;
      }
      cvt9_k<<<dim3(2048, 9), blk, 0, stream>>>(cd);
    }
    for (int d = 0; d < 4; d++) {
      const bf16_t* wq_d = wq_c + (long)d * 3145728;
      Ptr4 bq{{wq_d, wq_d, wq_d, wq_d}};
      gemm_bt<4><<<dim3(24, 32, 1), blk, 0, stream>>>(
          x_c, 0, 1024, bq, 1024, qk_d, 0, 2048, 1024, 0, nullptr, nullptr,
          vt_d, 0, d);
      attn_k<<<dim3(4, 64), blk, 0, stream>>>(qk_d, 0, vt_d, 0,
                                              y + (long)d * sY, 0, d);
    }
    {
      Ptr4 b4{{wo_c, wo_c + 1048576, wo_c + 2097152, wo_c + 3145728}};
      gemm_bt<0><<<dim3(8, 32, 4), blk, 0, stream>>>(
          y, sY, 1024, b4, 1024, concat, 1024, 4096, 1024, 0, nullptr, nullptr,
          nullptr, 0, 0);
    }
    {
      CvtDesc cd;
      for (int s = 0; s < 9; s++) cd.n8[s] = 0;
      cd.src[0] = wgate_f; cd.dst[0] = wg_c; cd.n8[0] = 16777216 / 8;
      cvt9_k<<<dim3(8192, 1), blk, 0, stream>>>(cd);
    }
    {
      Ptr4 b4{{wg_c, wg_c, wg_c, wg_c}};
      gemm_bt<1><<<dim3(32, 32, 1), blk, 0, stream>>>(
          concat, 0, 4096, b4, 4096, gated, 0, 4096, 4096, 0, bgate_f, concat,
          nullptr, 0, 0);
    }
    {
      CvtDesc cd;
      for (int s = 0; s < 9; s++) cd.n8[s] = 0;
      cd.src[0] = wout_f; cd.dst[0] = wout_c; cd.n8[0] = 4194304 / 8;
      cvt9_k<<<dim3(2048, 1), blk, 0, stream>>>(cd);
    }
    {
      Ptr4 b4{{wout_c, wout_c, wout_c, wout_c}};
      gemm_bt<3><<<dim3(8, 32, 2), blk, 0, stream>>>(
          gated, 0, 4096, b4, 4096, part, (long)4096 * 1024, 1024, 2048, 2048,
          nullptr, nullptr, nullptr, 0, 0);
    }
    rmsnorm_k<<<dim3(4096), blk, 0, stream>>>(part, part + (long)4096 * 1024,
                                              nullptr, nullptr,
                                              xf, normw_f, (float*)d_out);
  }
}

// Round 5
// 650.030 us; speedup vs baseline: 1.1148x; 1.1148x over previous
//
#include <hip/hip_runtime.h>
#include <hip/hip_bf16.h>
#include <math.h>

// ---------------------------------------------------------------------------
// MultiDirectionalGridAttention. FP32 in/out; bf16 MFMA core, fp32 accum.
// B=4, T=1024 (32x32 grid), D=1024, NH=16, hd=64.
//
// R13 = R12 resubmitted (previous bench failed on container acquisition, not
// kernel verification). attn spill fixed vs R11: launch_bounds(256,3) (R11's
// (256,4) forced VGPR=64 -> scratch spill, 392MB writes). Load balance via
// 3-way uniform q-tile grouping per (dir,b,h): {7,3},{6,4},{5,2,1,0} = 24
// k-tile-units each; grid (3,256) = 768 blocks = exactly 3/CU. qt from a
// branchless formula (no runtime-indexed local array). XCD swizzle bijective
// (768 % 8 == 0). Keeps: K pre-scaled 0.125 at qkv, boundary-only causal
// mask, defer-rescale, reg-prefetch, gemm_bt2 8-phase everywhere.
//
// Batched ws (168 MB): [0,8)x_c->wout_c  [8,32)wq_c  [32,40)wo_c
//   [40,104) qk 4x16MB (pos-order [Q|K], ldc 2048) -> concat[40,72), wg[72,104)
//       -> part4 [40,104) (4x16MB, after gate)
//   [104,136) vt 4x8MB  [136,168) y->gated
// ---------------------------------------------------------------------------

typedef __bf16 bf16_t;
typedef __bf16 bf16x4 __attribute__((ext_vector_type(4)));
typedef __bf16 bf16x8 __attribute__((ext_vector_type(8)));
typedef float  f32x4  __attribute__((ext_vector_type(4)));

#define MFMA16(a, b, c) __builtin_amdgcn_mfma_f32_16x16x32_bf16((a), (b), (c), 0, 0, 0)

__device__ __forceinline__ void async16(const bf16_t* g, bf16_t* l) {
  __builtin_amdgcn_global_load_lds((const __attribute__((address_space(1))) void*)g,
                                   (__attribute__((address_space(3))) void*)l,
                                   16, 0, 0);
}

// 16-lane (DPP row) all-reduce: xor1, xor2 quad-perms then row_ror:4, row_ror:8.
__device__ __forceinline__ float dpp_max16(float x) {
  float t;
  t = __builtin_bit_cast(float, __builtin_amdgcn_update_dpp(0, __builtin_bit_cast(int, x), 0xB1, 0xF, 0xF, true));
  x = fmaxf(x, t);
  t = __builtin_bit_cast(float, __builtin_amdgcn_update_dpp(0, __builtin_bit_cast(int, x), 0x4E, 0xF, 0xF, true));
  x = fmaxf(x, t);
  t = __builtin_bit_cast(float, __builtin_amdgcn_update_dpp(0, __builtin_bit_cast(int, x), 0x124, 0xF, 0xF, true));
  x = fmaxf(x, t);
  t = __builtin_bit_cast(float, __builtin_amdgcn_update_dpp(0, __builtin_bit_cast(int, x), 0x128, 0xF, 0xF, true));
  x = fmaxf(x, t);
  return x;
}
__device__ __forceinline__ float dpp_sum16(float x) {
  float t;
  t = __builtin_bit_cast(float, __builtin_amdgcn_update_dpp(0, __builtin_bit_cast(int, x), 0xB1, 0xF, 0xF, true));
  x += t;
  t = __builtin_bit_cast(float, __builtin_amdgcn_update_dpp(0, __builtin_bit_cast(int, x), 0x4E, 0xF, 0xF, true));
  x += t;
  t = __builtin_bit_cast(float, __builtin_amdgcn_update_dpp(0, __builtin_bit_cast(int, x), 0x124, 0xF, 0xF, true));
  x += t;
  t = __builtin_bit_cast(float, __builtin_amdgcn_update_dpp(0, __builtin_bit_cast(int, x), 0x128, 0xF, 0xF, true));
  x += t;
  return x;
}

struct Ptr4 { const bf16_t* p[4]; };

// Causal-order position p <-> token t (involution).
__device__ __forceinline__ int perm_t(int p, int dir) {
  int q = (dir & 1) ? (1023 - p) : p;
  if (dir >= 2) q = ((q & 31) << 5) | (q >> 5);
  return q;
}

// ------------------- batched fp32 -> bf16 convert (<=9 segments) ------------
struct CvtDesc {
  const float* src[9];
  bf16_t* dst[9];
  int n8[9];
};

__device__ __forceinline__ void cvt8(const float* in, bf16_t* out, int i) {
  const float4 a = ((const float4*)in)[i * 2];
  const float4 b = ((const float4*)in)[i * 2 + 1];
  bf16x8 o;
  o[0] = (bf16_t)a.x; o[1] = (bf16_t)a.y; o[2] = (bf16_t)a.z; o[3] = (bf16_t)a.w;
  o[4] = (bf16_t)b.x; o[5] = (bf16_t)b.y; o[6] = (bf16_t)b.z; o[7] = (bf16_t)b.w;
  ((bf16x8*)out)[i] = o;
}

__global__ __launch_bounds__(256) void cvt9_k(CvtDesc d) {
  const int seg = blockIdx.y;
  const int i = blockIdx.x * 256 + threadIdx.x;
  if (i >= d.n8[seg]) return;
  cvt8(d.src[seg], d.dst[seg], i);
}

// ---------------------------------------------------------------------------
// gemm_bt2: C = A * B^T, bf16 in, fp32 acc. 256x256 tile, BK=64, 512 threads,
// 8 waves (2M x 4N), each wave owns 128x64 output (acc[8][4] f32x4).
// Double-buffered 128 KiB LDS; per K-tile 4 phases of
//   {ds_read frags ; stage half-tile ; s_barrier ; lgkmcnt(0) ;
//    setprio(1) ; 16 MFMA ; setprio(0) ; s_barrier}
// Prefetch loads for tile kt+1 issued in phases 0-1 of kt; the end-of-tile
// vmcnt(0) folded into phase-3's trailing barrier. LDS rows 128B, 16B-block
// XOR swizzle blk' = blk ^ (row&7) (both-sides).
// MODE 0: bf16 C.  MODE 1: sigmoid-gate vs gin.  MODE 3: fp32 split-K part.
// MODE 4: qkv. K block (bn in [1024,2048)) pre-scaled by 0.125.
// ---------------------------------------------------------------------------
template <int MODE>
__global__ __launch_bounds__(512, 2) void gemm_bt2(
    const bf16_t* __restrict__ A, long sAz, int lda,
    Ptr4 B4, int ldb,
    void* __restrict__ Cv, long sCz, int ldc, int K, int koff,
    const float* __restrict__ bias,
    const bf16_t* __restrict__ gin,
    bf16_t* __restrict__ vtp, long sVz, int dirbase) {
  constexpr int BM = 256, BN = 256, BK = 64;
  (void)BM; (void)BN;
  __shared__ __align__(16) char smem[131072];

  const int z = blockIdx.z;
  const bf16_t* Ap = A + (long)z * sAz;
  const bf16_t* Bp = B4.p[z];
  const int tid = threadIdx.x;
  const int lane = tid & 63;
  const int wave = tid >> 6;
  const int l15 = lane & 15, qd = lane >> 4;
  const int wm = wave >> 2, wn = wave & 3;  // 2 x 4 wave grid
  const int bm = blockIdx.y * 256, bn = blockIdx.x * 256;
  const int kz = (MODE == 3) ? z * koff : 0;
  const int NT = K / BK;

  // ---- staging thread-constants (pre-swizzled global source) ----
  const int row0 = tid >> 3;                          // 0..63
  const int blkp = ((tid & 7) ^ (row0 & 7)) * 8;      // swizzled 16B block (elems)
  const bf16_t* gA = Ap + (long)(bm + row0) * lda + blkp + kz;
  const bf16_t* gB = Bp + (long)(bn + row0) * ldb + blkp + kz;
  char* const sm = (char*)smem;
  const int ldsT = tid * 16;                          // lane-linear dest

  // ---- fragment read bases (byte offsets inside one buffer) ----
  const int xorv = (l15 & 7) << 4;
  const int aBase = (wm * 128 + l15) * 128;           // A region [0, 32KB)
  const int bBase = 32768 + (wn * 64 + l15) * 128;    // B region [32KB, 64KB)
  const int colk0 = (qd * 16) ^ xorv;
  const int colk1 = (64 + qd * 16) ^ xorv;

  f32x4 acc[8][4];
#pragma unroll
  for (int i = 0; i < 8; i++)
#pragma unroll
    for (int j = 0; j < 4; j++) acc[i][j] = (f32x4){0.f, 0.f, 0.f, 0.f};

  // ---- prologue: stage tile 0 into buf 0 ----
#pragma unroll
  for (int u = 0; u < 4; u++)
    async16(gA + (long)(u * 64) * lda, (bf16_t*)(sm + u * 8192 + ldsT));
#pragma unroll
  for (int u = 0; u < 4; u++)
    async16(gB + (long)(u * 64) * ldb, (bf16_t*)(sm + 32768 + u * 8192 + ldsT));
  asm volatile("s_waitcnt vmcnt(0)" ::: "memory");
  __builtin_amdgcn_s_barrier();

  for (int kt = 0; kt < NT; ++kt) {
    const int c = kt & 1;
    const char* sa = sm + c * 65536;
    const int nb = (c ^ 1) * 65536;
    const long ko = (long)(kt + 1) * BK;
    bf16x8 bF[4][2];
#pragma unroll
    for (int p = 0; p < 4; ++p) {
      // -- ds-read this phase's fragments --
      if (p == 0) {
#pragma unroll
        for (int n = 0; n < 4; ++n) {
          bF[n][0] = *(const bf16x8*)(sa + bBase + n * 2048 + colk0);
          bF[n][1] = *(const bf16x8*)(sa + bBase + n * 2048 + colk1);
        }
      }
      bf16x8 aF[2][2];
#pragma unroll
      for (int mm = 0; mm < 2; ++mm) {
        aF[mm][0] = *(const bf16x8*)(sa + aBase + (p * 2 + mm) * 2048 + colk0);
        aF[mm][1] = *(const bf16x8*)(sa + aBase + (p * 2 + mm) * 2048 + colk1);
      }
      // -- stage next tile (A halves in phase 0, B halves in phase 1) --
      if (kt + 1 < NT) {
        if (p == 0) {
#pragma unroll
          for (int u = 0; u < 4; u++)
            async16(gA + (long)(u * 64) * lda + ko,
                    (bf16_t*)(sm + nb + u * 8192 + ldsT));
        } else if (p == 1) {
#pragma unroll
          for (int u = 0; u < 4; u++)
            async16(gB + (long)(u * 64) * ldb + ko,
                    (bf16_t*)(sm + nb + 32768 + u * 8192 + ldsT));
        }
      }
      __builtin_amdgcn_s_barrier();
      asm volatile("s_waitcnt lgkmcnt(0)" ::: "memory");
      __builtin_amdgcn_s_setprio(1);
#pragma unroll
      for (int kh = 0; kh < 2; ++kh)
#pragma unroll
        for (int mm = 0; mm < 2; ++mm)
#pragma unroll
          for (int n = 0; n < 4; ++n)
            acc[p * 2 + mm][n] =
                MFMA16(aF[mm][kh], bF[n][kh], acc[p * 2 + mm][n]);
      __builtin_amdgcn_s_setprio(0);
      if (p == 3 && kt + 1 < NT)  // next tile resident before its phase-0 reads
        asm volatile("s_waitcnt vmcnt(0)" ::: "memory");
      __builtin_amdgcn_s_barrier();
    }
  }

  // ---- epilogue: 4 passes of 64 rows through fp32 LDS bounce (overlay) ----
  if constexpr (MODE == 4) {
    const int dir = dirbase + z;
    if (bn < 2048) {  // Q,K: MODE-0-style bounce, row-permuted coalesced store
      bf16_t* qkz = (bf16_t*)Cv + (long)z * sCz;
      const float ksc = (bn >= 1024) ? 0.125f : 1.0f;  // pre-scale K by 1/8
      float* sC = (float*)smem;
#pragma unroll
      for (int p = 0; p < 4; ++p) {
        if (p) __syncthreads();
        if (wm == (p >> 1)) {
#pragma unroll
          for (int mm = 0; mm < 4; ++mm) {
            const int m = (p & 1) * 4 + mm;
#pragma unroll
            for (int n = 0; n < 4; ++n)
#pragma unroll
              for (int r = 0; r < 4; ++r)
                sC[(mm * 16 + qd * 4 + r) * 260 + wn * 64 + n * 16 + l15] =
                    acc[m][n][r];
          }
        }
        __syncthreads();
#pragma unroll
        for (int i = 0; i < 8; ++i) {
          const int idx = i * 512 + tid;
          const int rl = idx >> 6, c4 = (idx & 63) * 4;
          const float4 v4 = *(const float4*)&sC[rl * 260 + c4];
          const int grow = bm + p * 64 + rl;
          const int prow = (grow & ~1023) | perm_t(grow & 1023, dir);
          bf16x4 o;
          o[0] = (bf16_t)(v4.x * ksc); o[1] = (bf16_t)(v4.y * ksc);
          o[2] = (bf16_t)(v4.z * ksc); o[3] = (bf16_t)(v4.w * ksc);
          *(bf16x4*)(qkz + (long)prow * ldc + bn + c4) = o;
        }
      }
    } else {  // V: transposed bounce sCt[256 cols][68], pos-major stores
      bf16_t* vz = vtp + (long)z * sVz;
      float* sCt = (float*)smem;
#pragma unroll
      for (int p = 0; p < 4; ++p) {
        if (p) __syncthreads();
        if (wm == (p >> 1)) {
#pragma unroll
          for (int mm = 0; mm < 4; ++mm) {
            const int m = (p & 1) * 4 + mm;
#pragma unroll
            for (int n = 0; n < 4; ++n)
#pragma unroll
              for (int r = 0; r < 4; ++r)
                sCt[(wn * 64 + n * 16 + l15) * 68 + mm * 16 + qd * 4 + r] =
                    acc[m][n][r];
          }
        }
        __syncthreads();
#pragma unroll
        for (int i = 0; i < 8; ++i) {
          const int idx = i * 512 + tid;         // 4096 = 256 cols x 16 chunks
          const int col = idx >> 4, tq = idx & 15;
          const float4 v4 = *(const float4*)&sCt[col * 68 + tq * 4];
          const int t0 = (bm & 1023) + p * 64 + tq * 4;
          const int bb = bm >> 10;
          const int ch = bn + col - 2048;
          bf16_t* vrow =
              vz + (((long)bb * 16 + (ch >> 6)) * 64 + (ch & 63)) * 1024;
          if (dir == 0) {
            bf16x4 o;
            o[0] = (bf16_t)v4.x; o[1] = (bf16_t)v4.y;
            o[2] = (bf16_t)v4.z; o[3] = (bf16_t)v4.w;
            *(bf16x4*)(vrow + t0) = o;
          } else if (dir == 1) {
            bf16x4 o;
            o[0] = (bf16_t)v4.w; o[1] = (bf16_t)v4.z;
            o[2] = (bf16_t)v4.y; o[3] = (bf16_t)v4.x;
            *(bf16x4*)(vrow + (1020 - t0)) = o;
          } else {
            vrow[perm_t(t0 + 0, dir)] = (bf16_t)v4.x;
            vrow[perm_t(t0 + 1, dir)] = (bf16_t)v4.y;
            vrow[perm_t(t0 + 2, dir)] = (bf16_t)v4.z;
            vrow[perm_t(t0 + 3, dir)] = (bf16_t)v4.w;
          }
        }
      }
    }
  } else {
    float* sC = (float*)smem;
#pragma unroll
    for (int p = 0; p < 4; ++p) {
      if (p) __syncthreads();
      if (wm == (p >> 1)) {
#pragma unroll
        for (int mm = 0; mm < 4; ++mm) {
          const int m = (p & 1) * 4 + mm;
#pragma unroll
          for (int n = 0; n < 4; ++n)
#pragma unroll
            for (int r = 0; r < 4; ++r)
              sC[(mm * 16 + qd * 4 + r) * 260 + wn * 64 + n * 16 + l15] =
                  acc[m][n][r];
        }
      }
      __syncthreads();
#pragma unroll
      for (int i = 0; i < 8; ++i) {
        const int idx = i * 512 + tid;
        const int rl = idx >> 6, c4 = (idx & 63) * 4;
        const float4 v4 = *(const float4*)&sC[rl * 260 + c4];
        const int grow = bm + p * 64 + rl;
        const int gcol = bn + c4;
        const long goff = (long)grow * ldc + gcol;
        if constexpr (MODE == 0) {
          bf16x4 o;
          o[0] = (bf16_t)v4.x; o[1] = (bf16_t)v4.y;
          o[2] = (bf16_t)v4.z; o[3] = (bf16_t)v4.w;
          *(bf16x4*)((bf16_t*)Cv + (long)z * sCz + goff) = o;
        } else if constexpr (MODE == 1) {
          const float4 bb = *(const float4*)&bias[gcol];
          const bf16x4 gv = *(const bf16x4*)&gin[goff];
          bf16x4 o;
          o[0] = (bf16_t)((float)gv[0] / (1.f + __expf(-(v4.x + bb.x))));
          o[1] = (bf16_t)((float)gv[1] / (1.f + __expf(-(v4.y + bb.y))));
          o[2] = (bf16_t)((float)gv[2] / (1.f + __expf(-(v4.z + bb.z))));
          o[3] = (bf16_t)((float)gv[3] / (1.f + __expf(-(v4.w + bb.w))));
          *(bf16x4*)((bf16_t*)Cv + goff) = o;
        } else {
          *(float4*)((float*)Cv + (long)z * sCz + goff) = v4;
        }
      }
    }
  }
}

// ---------------------------------------------------------------------------
// Legacy 128x128 gemm (m97 structure) — retained for the low-ws fallback path.
// ---------------------------------------------------------------------------
template <int MODE>
__global__ __launch_bounds__(256) void gemm_bt(
    const bf16_t* __restrict__ A, long sAz, int lda,
    Ptr4 B4, int ldb,
    void* __restrict__ Cv, long sCz, int ldc, int K, int koff,
    const float* __restrict__ bias,
    const bf16_t* __restrict__ gin,
    bf16_t* __restrict__ vtp, long sVz, int dirbase) {
  constexpr int BM = 128, BN = 128, BK = 32;
  __shared__ __align__(16) char smem[18432];
  bf16_t* sA = (bf16_t*)smem;
  bf16_t* sB = (bf16_t*)(smem + BM * BK * 2);
  float* sC = (float*)smem;

  const int z = blockIdx.z;
  const bf16_t* Ap = A + (long)z * sAz;
  const bf16_t* Bp = B4.p[z];
  const int tid = threadIdx.x;
  const int wave = tid >> 6, lane = tid & 63;
  const int lane15 = lane & 15, quad = lane >> 4;
  const int bm = blockIdx.y * BM, bn = blockIdx.x * BN;
  const int wm = (wave >> 1) * 64, wn = (wave & 1) * 64;

  f32x4 acc[4][4];
#pragma unroll
  for (int i = 0; i < 4; i++)
#pragma unroll
    for (int j = 0; j < 4; j++) acc[i][j] = (f32x4){0.f, 0.f, 0.f, 0.f};

  const int srow = wave * 16 + (lane >> 2);
  const int skoff = (lane & 3) * 8;
  const int kz = (MODE == 3) ? z * koff : 0;
  const bf16_t* ga = Ap + (long)(bm + srow) * lda + skoff + kz;
  const bf16_t* gb = Bp + (long)(bn + srow) * ldb + skoff + kz;
  bf16_t* la = &sA[srow * BK + skoff];
  bf16_t* lb = &sB[srow * BK + skoff];

  for (int k0 = 0; k0 < K; k0 += BK) {
    __syncthreads();
    async16(ga + k0, la);
    async16(ga + k0 + (long)64 * lda, la + 64 * BK);
    async16(gb + k0, lb);
    async16(gb + k0 + (long)64 * ldb, lb + 64 * BK);
    __syncthreads();

    bf16x8 af[4], bfv[4];
#pragma unroll
    for (int i = 0; i < 4; i++)
      af[i] = *(const bf16x8*)&sA[(wm + i * 16 + lane15) * BK + quad * 8];
#pragma unroll
    for (int j = 0; j < 4; j++)
      bfv[j] = *(const bf16x8*)&sB[(wn + j * 16 + lane15) * BK + quad * 8];
#pragma unroll
    for (int i = 0; i < 4; i++)
#pragma unroll
      for (int j = 0; j < 4; j++)
        acc[i][j] = MFMA16(af[i], bfv[j], acc[i][j]);
  }

  __syncthreads();  // all waves done reading sA/sB before the sC overlay

  // ------------- epilogue -------------
  if constexpr (MODE == 4) {
    const int dir = dirbase + z;
    if (bn < 2048) {  // Q,K: 4 passes of 16+16 rows, row-permuted store
      bf16_t* qkz = (bf16_t*)Cv + (long)z * sCz;
      const float ksc = (bn >= 1024) ? 0.125f : 1.0f;  // pre-scale K by 1/8
#pragma unroll
      for (int p = 0; p < 4; p++) {
        if (p) __syncthreads();
        const int sr = (wm >> 2) + quad * 4;  // wm=0 -> 0..15, wm=64 -> 16..31
#pragma unroll
        for (int r = 0; r < 4; r++)
#pragma unroll
          for (int j = 0; j < 4; j++)
            sC[(sr + r) * 144 + wn + j * 16 + lane15] = acc[p][j][r];
        __syncthreads();
#pragma unroll
        for (int c = 0; c < 4; c++) {
          const int idx = c * 256 + tid;
          const int srr = idx >> 5, chunk = idx & 31;
          const float4 v4 = *(const float4*)&sC[srr * 144 + chunk * 4];
          const int grow = bm + p * 16 + (srr & 15) + (srr >> 4) * 64;
          const int prow = (grow & ~1023) | perm_t(grow & 1023, dir);
          bf16x4 o;
          o[0] = (bf16_t)(v4.x * ksc); o[1] = (bf16_t)(v4.y * ksc);
          o[2] = (bf16_t)(v4.z * ksc); o[3] = (bf16_t)(v4.w * ksc);
          *(bf16x4*)(qkz + (long)prow * 2048 + bn + chunk * 4) = o;
        }
      }
    } else {  // V: 4 passes (row-half p x col-half q) -> vt[b][h][d][pos]
      bf16_t* vz = vtp + (long)z * sVz;
      float* sCt = sC;  // [col 0..63][tok-compressed 0..63], stride 68
#pragma unroll
      for (int p = 0; p < 2; p++)
#pragma unroll
        for (int q = 0; q < 2; q++) {
          if (p || q) __syncthreads();
          if ((wave & 1) == q) {  // only waves with wn == 64q hold these cols
#pragma unroll
            for (int ii = 0; ii < 2; ii++) {
              const int i = 2 * p + ii;
              const int srb = (wm >> 1) + ii * 16 + quad * 4;
#pragma unroll
              for (int r = 0; r < 4; r++)
#pragma unroll
                for (int j = 0; j < 4; j++)
                  sCt[(j * 16 + lane15) * 68 + srb + r] = acc[i][j][r];
            }
          }
          __syncthreads();
#pragma unroll
          for (int c = 0; c < 4; c++) {
            const int idx = c * 256 + tid;
            const int col = idx >> 4, tq = idx & 15;
            const int srr0 = (tq & 7) * 4 + (tq >> 3) * 32;
            const float4 v4 = *(const float4*)&sCt[col * 68 + srr0];
            const int t0 = (bm & 1023) + p * 32 + (srr0 & 31) + (srr0 >> 5) * 64;
            const int bb = bm >> 10;
            const int ch = bn + 64 * q + col - 2048;
            bf16_t* vrow =
                vz + (((long)bb * 16 + (ch >> 6)) * 64 + (ch & 63)) * 1024;
            if (dir == 0) {
              bf16x4 o;
              o[0] = (bf16_t)v4.x; o[1] = (bf16_t)v4.y;
              o[2] = (bf16_t)v4.z; o[3] = (bf16_t)v4.w;
              *(bf16x4*)(vrow + t0) = o;
            } else if (dir == 1) {
              bf16x4 o;
              o[0] = (bf16_t)v4.w; o[1] = (bf16_t)v4.z;
              o[2] = (bf16_t)v4.y; o[3] = (bf16_t)v4.x;
              *(bf16x4*)(vrow + (1020 - t0)) = o;
            } else {
              vrow[perm_t(t0 + 0, dir)] = (bf16_t)v4.x;
              vrow[perm_t(t0 + 1, dir)] = (bf16_t)v4.y;
              vrow[perm_t(t0 + 2, dir)] = (bf16_t)v4.z;
              vrow[perm_t(t0 + 3, dir)] = (bf16_t)v4.w;
            }
          }
        }
    }
  } else {
#pragma unroll
    for (int p = 0; p < 4; p++) {
      if (p) __syncthreads();
      const int sr = (wm >> 2) + quad * 4;
#pragma unroll
      for (int r = 0; r < 4; r++)
#pragma unroll
        for (int j = 0; j < 4; j++)
          sC[(sr + r) * 144 + wn + j * 16 + lane15] = acc[p][j][r];
      __syncthreads();
#pragma unroll
      for (int c = 0; c < 4; c++) {
        const int idx = c * 256 + tid;
        const int srr = idx >> 5, chunk = idx & 31;
        const float4 v4 = *(const float4*)&sC[srr * 144 + chunk * 4];
        const int grow = bm + p * 16 + (srr & 15) + (srr >> 4) * 64;
        const int gcol = bn + chunk * 4;
        const long goff = (long)grow * ldc + gcol;
        if constexpr (MODE == 0) {
          bf16x4 o;
          o[0] = (bf16_t)v4.x; o[1] = (bf16_t)v4.y;
          o[2] = (bf16_t)v4.z; o[3] = (bf16_t)v4.w;
          *(bf16x4*)((bf16_t*)Cv + (long)z * sCz + goff) = o;
        } else if constexpr (MODE == 1) {
          const float4 bb = *(const float4*)&bias[gcol];
          const bf16x4 gv = *(const bf16x4*)&gin[goff];
          bf16x4 o;
          o[0] = (bf16_t)((float)gv[0] / (1.f + __expf(-(v4.x + bb.x))));
          o[1] = (bf16_t)((float)gv[1] / (1.f + __expf(-(v4.y + bb.y))));
          o[2] = (bf16_t)((float)gv[2] / (1.f + __expf(-(v4.z + bb.z))));
          o[3] = (bf16_t)((float)gv[3] / (1.f + __expf(-(v4.w + bb.w))));
          *(bf16x4*)((bf16_t*)Cv + goff) = o;
        } else {
          *(float4*)((float*)Cv + (long)z * sCz + goff) = v4;
        }
      }
    }
  }
}

// ---------------------------------------------------------------------------
// Flash attention, pure-causal in position space (no perm in hot loop).
// Block = 4 waves x 32 q-rows; grid (3, Ybh) = 3 blocks per (dir,b,h), each
// running a uniform 24 k-tile-units of q-tiles: bx=0 -> {7,3}, bx=1 -> {6,4},
// bx=2 -> {5,2,1,0}. 768 blocks = exactly 3/CU at launch_bounds(256,3).
// XCD swizzle (768 % 8 == 0, bijective) keeps one (dir,b,h)'s blocks on one
// XCD. K pre-scaled by 0.125; mask on boundary tiles only; defer-rescale.
// ---------------------------------------------------------------------------
__global__ __launch_bounds__(256, 3) void attn_k(
    const bf16_t* __restrict__ qk, long sQz,
    const bf16_t* __restrict__ vt, long sVz,
    bf16_t* __restrict__ y, long sYz, int dir0) {
  const int p0 = blockIdx.y * 3 + blockIdx.x;
  const int chunk = (gridDim.y * 3) >> 3;        // blocks per XCD
  const int lg = (p0 & 7) * chunk + (p0 >> 3);
  const int bx = lg % 3, by = lg / 3;
  const int zi = by >> 6;
  const int bh = by & 63;
  const int dir = dir0 + zi;
  const int b = bh >> 4, h = bh & 15;
  const int tid = threadIdx.x;
  const int wave = tid >> 6, lane = tid & 63;
  const int lane15 = lane & 15, quad = lane >> 4;
  const int hoff = h * 64;
  const bf16_t* base = qk + (long)zi * sQz + (long)b * 1024 * 2048;
  const bf16_t* vth = vt + (long)zi * sVz + ((long)b * 16 + h) * 64 * 1024;
  bf16_t* yd = y + (long)zi * sYz;

  __shared__ __align__(16) bf16_t sK[64 * 72];
  __shared__ __align__(16) bf16_t sVt[64 * 72];
  __shared__ __align__(16) bf16_t sP[4][32 * 72];

  const int krow = tid >> 3, kd = (tid & 7) * 8;   // K: 32 rows x 128B per pass
  const int vd = tid >> 2, pc = (tid & 3) * 8;     // V: 64 d-rows x 64B per pass
  const bf16_t* kb_g = base + 1024 + hoff;
  const float FNEG = -1e30f;

  const int np = (bx == 2) ? 4 : 2;
  for (int pass = 0; pass < np; ++pass) {
    // bx=0: 7,3   bx=1: 6,4   bx=2: 5,2,1,0   (heavy first; branchless)
    const int qt = (bx == 0) ? (7 - 4 * pass)
                 : (bx == 1) ? (6 - 2 * pass)
                             : ((pass == 0) ? 5 : 3 - pass);

    // Q fragments: 2 row-groups of 16, A-layout (m=lane15, k=quad*8+j)
    bf16x8 qa[2][2];
#pragma unroll
    for (int g = 0; g < 2; g++) {
      const int row = qt * 128 + wave * 32 + g * 16 + lane15;
      qa[g][0] = *(const bf16x8*)(base + (long)row * 2048 + hoff + quad * 8);
      qa[g][1] = *(const bf16x8*)(base + (long)row * 2048 + hoff + 32 + quad * 8);
    }

    float mrow[2][4], lrow[2][4];
    f32x4 o[2][4];
#pragma unroll
    for (int g = 0; g < 2; g++)
#pragma unroll
      for (int r = 0; r < 4; r++) { mrow[g][r] = FNEG; lrow[g][r] = 0.f; }
#pragma unroll
    for (int g = 0; g < 2; g++)
#pragma unroll
      for (int d4 = 0; d4 < 4; d4++) o[g][d4] = (f32x4){0.f, 0.f, 0.f, 0.f};

    // preload tile 0
    bf16x8 kA = *(const bf16x8*)(kb_g + (long)krow * 2048 + kd);
    bf16x8 kB = *(const bf16x8*)(kb_g + (long)(32 + krow) * 2048 + kd);
    bf16x8 vA = *(const bf16x8*)(vth + (long)vd * 1024 + pc);
    bf16x8 vB = *(const bf16x8*)(vth + (long)vd * 1024 + 32 + pc);

    const int qlo = qt * 128 + wave * 32;        // wave's lowest q-row
    const int ktiles = 2 * qt + 2;
    for (int kt = 0; kt < ktiles; kt++) {
      __syncthreads();  // prev tile's LDS reads done
      *(bf16x8*)&sK[krow * 72 + kd] = kA;
      *(bf16x8*)&sK[(krow + 32) * 72 + kd] = kB;
      *(bf16x8*)&sVt[vd * 72 + pc] = vA;
      *(bf16x8*)&sVt[vd * 72 + 32 + pc] = vB;
      __syncthreads();  // staging visible
      if (kt + 1 < ktiles) {  // prefetch next tile into regs (overlaps compute)
        const int nb = (kt + 1) * 64;
        kA = *(const bf16x8*)(kb_g + (long)(nb + krow) * 2048 + kd);
        kB = *(const bf16x8*)(kb_g + (long)(nb + 32 + krow) * 2048 + kd);
        vA = *(const bf16x8*)(vth + (long)vd * 1024 + nb + pc);
        vB = *(const bf16x8*)(vth + (long)vd * 1024 + nb + 32 + pc);
      }
      const int kbase = kt * 64;

      // S = Q K^T (K pre-scaled): per g, 4 key-groups x 2 k-chunks
      bf16x8 kb[4][2];
#pragma unroll
      for (int ns = 0; ns < 4; ns++) {
        kb[ns][0] = *(const bf16x8*)&sK[(ns * 16 + lane15) * 72 + quad * 8];
        kb[ns][1] = *(const bf16x8*)&sK[(ns * 16 + lane15) * 72 + 32 + quad * 8];
      }
      f32x4 s[2][4];
#pragma unroll
      for (int g = 0; g < 2; g++)
#pragma unroll
        for (int ns = 0; ns < 4; ns++) {
          f32x4 t = (f32x4){0.f, 0.f, 0.f, 0.f};
          t = MFMA16(qa[g][0], kb[ns][0], t);
          t = MFMA16(qa[g][1], kb[ns][1], t);
          s[g][ns] = t;
        }
      // causal mask (boundary tiles only; wave-uniform test)
      if (kbase + 63 > qlo) {
#pragma unroll
        for (int g = 0; g < 2; g++) {
          const int qc = qlo + g * 16 + quad * 4;
#pragma unroll
          for (int ns = 0; ns < 4; ns++) {
            const int kp = kbase + ns * 16 + lane15;
#pragma unroll
            for (int r = 0; r < 4; r++)
              if (kp > qc + r) s[g][ns][r] = FNEG;
          }
        }
      }
      // online softmax: tile max, defer-rescale if no new max
      float tm[2][4];
#pragma unroll
      for (int g = 0; g < 2; g++)
#pragma unroll
        for (int r = 0; r < 4; r++) {
          float t = fmaxf(fmaxf(s[g][0][r], s[g][1][r]),
                          fmaxf(s[g][2][r], s[g][3][r]));
          tm[g][r] = dpp_max16(t);
        }
      bool up = false;
#pragma unroll
      for (int g = 0; g < 2; g++)
#pragma unroll
        for (int r = 0; r < 4; r++) up = up || (tm[g][r] > mrow[g][r]);
      if (__any(up)) {
#pragma unroll
        for (int g = 0; g < 2; g++) {
          float alpha[4];
#pragma unroll
          for (int r = 0; r < 4; r++) {
            const float mn = fmaxf(mrow[g][r], tm[g][r]);
            alpha[r] = __expf(mrow[g][r] - mn);
            mrow[g][r] = mn;
          }
#pragma unroll
          for (int r = 0; r < 4; r++) lrow[g][r] *= alpha[r];
#pragma unroll
          for (int d4 = 0; d4 < 4; d4++)
#pragma unroll
            for (int r = 0; r < 4; r++) o[g][d4][r] *= alpha[r];
        }
      }
#pragma unroll
      for (int g = 0; g < 2; g++) {
#pragma unroll
        for (int ns = 0; ns < 4; ns++)
#pragma unroll
          for (int r = 0; r < 4; r++)
            s[g][ns][r] = __expf(s[g][ns][r] - mrow[g][r]);
#pragma unroll
        for (int r = 0; r < 4; r++) {
          float ts = (s[g][0][r] + s[g][1][r]) + (s[g][2][r] + s[g][3][r]);
          lrow[g][r] += dpp_sum16(ts);
        }
        // P: C-layout -> bf16 A-layout via per-wave LDS scratch
#pragma unroll
        for (int ns = 0; ns < 4; ns++)
#pragma unroll
          for (int r = 0; r < 4; r++)
            sP[wave][(g * 16 + quad * 4 + r) * 72 + ns * 16 + lane15] =
                (bf16_t)s[g][ns][r];
      }
      // PV
      bf16x8 vb[4][2];
#pragma unroll
      for (int d4 = 0; d4 < 4; d4++) {
        vb[d4][0] = *(const bf16x8*)&sVt[(d4 * 16 + lane15) * 72 + quad * 8];
        vb[d4][1] = *(const bf16x8*)&sVt[(d4 * 16 + lane15) * 72 + 32 + quad * 8];
      }
#pragma unroll
      for (int g = 0; g < 2; g++) {
        const bf16x8 pa0 = *(const bf16x8*)&sP[wave][(g * 16 + lane15) * 72 + quad * 8];
        const bf16x8 pa1 = *(const bf16x8*)&sP[wave][(g * 16 + lane15) * 72 + 32 + quad * 8];
#pragma unroll
        for (int d4 = 0; d4 < 4; d4++) {
          o[g][d4] = MFMA16(pa0, vb[d4][0], o[g][d4]);
          o[g][d4] = MFMA16(pa1, vb[d4][1], o[g][d4]);
        }
      }
    }

    // epilogue: normalize, bounce through sP (per-wave), vector store + perm
#pragma unroll
    for (int g = 0; g < 2; g++)
#pragma unroll
      for (int r = 0; r < 4; r++) {
        const float rinv = 1.f / fmaxf(lrow[g][r], 1e-20f);
#pragma unroll
        for (int d4 = 0; d4 < 4; d4++)
          sP[wave][(g * 16 + quad * 4 + r) * 72 + d4 * 16 + lane15] =
              (bf16_t)(o[g][d4][r] * rinv);
      }
#pragma unroll
    for (int g = 0; g < 2; g++) {
      const bf16x8 o0 = *(const bf16x8*)&sP[wave][(g * 16 + lane15) * 72 + quad * 16];
      const bf16x8 o1 = *(const bf16x8*)&sP[wave][(g * 16 + lane15) * 72 + quad * 16 + 8];
      const int tok = perm_t(qt * 128 + wave * 32 + g * 16 + lane15, dir);
      bf16_t* yr = yd + ((long)b * 1024 + tok) * 1024 + hoff + quad * 16;
      *(bf16x8*)yr = o0;
      *(bf16x8*)(yr + 8) = o1;
    }
  }
}

// ---------------------------------------------------------------------------
// RMSNorm over rows of 1024: v = P0 + P1 (+ P2 + P3) + x (split-K reduce +
// residual). p2/p3 may be null (2-way split fallback).
// ---------------------------------------------------------------------------
__global__ __launch_bounds__(256) void rmsnorm_k(const float* __restrict__ p0,
                                                 const float* __restrict__ p1,
                                                 const float* __restrict__ p2,
                                                 const float* __restrict__ p3,
                                                 const float* __restrict__ x,
                                                 const float* __restrict__ w,
                                                 float* __restrict__ out) {
  const int row = blockIdx.x, tid = threadIdx.x;
  const long off = (long)row * 1024;
  const float4 a = ((const float4*)(p0 + off))[tid];
  const float4 bq = ((const float4*)(p1 + off))[tid];
  const float4 c = ((const float4*)(x + off))[tid];
  float4 v;
  v.x = a.x + bq.x + c.x;
  v.y = a.y + bq.y + c.y;
  v.z = a.z + bq.z + c.z;
  v.w = a.w + bq.w + c.w;
  if (p2) {
    const float4 d = ((const float4*)(p2 + off))[tid];
    const float4 e = ((const float4*)(p3 + off))[tid];
    v.x += d.x + e.x;
    v.y += d.y + e.y;
    v.z += d.z + e.z;
    v.w += d.w + e.w;
  }
  float ss = v.x * v.x + v.y * v.y + v.z * v.z + v.w * v.w;
#pragma unroll
  for (int o2 = 32; o2 >= 1; o2 >>= 1) ss += __shfl_xor(ss, o2);
  __shared__ float wsum[4];
  if ((tid & 63) == 0) wsum[tid >> 6] = ss;
  __syncthreads();
  const float tot = wsum[0] + wsum[1] + wsum[2] + wsum[3];
  const float norm = rsqrtf(tot * (1.f / 1024.f) + 1e-6f);
  const float4 wv = ((const float4*)w)[tid];
  v.x = v.x * norm * wv.x;
  v.y = v.y * norm * wv.y;
  v.z = v.z * norm * wv.z;
  v.w = v.w * norm * wv.w;
  ((float4*)(out + off))[tid] = v;
}

// ---------------------------------------------------------------------------
extern "C" void kernel_launch(void* const* d_in, const int* in_sizes, int n_in,
                              void* d_out, int out_size, void* d_ws, size_t ws_size,
                              hipStream_t stream) {
  (void)in_sizes; (void)n_in; (void)out_size;
  const float* xf = (const float*)d_in[0];
  const float* wqkv_f[4] = {(const float*)d_in[1], (const float*)d_in[3],
                            (const float*)d_in[5], (const float*)d_in[7]};
  const float* wo_f[4] = {(const float*)d_in[2], (const float*)d_in[4],
                          (const float*)d_in[6], (const float*)d_in[8]};
  const float* wgate_f = (const float*)d_in[9];
  const float* bgate_f = (const float*)d_in[10];
  const float* wout_f = (const float*)d_in[11];
  const float* normw_f = (const float*)d_in[12];

  const long MB = 1l << 20;
  char* ws = (char*)d_ws;
  const dim3 blk(256);
  const dim3 blk2(512);
  const bool batched = ws_size >= (size_t)(168 * MB);
  const long sQK = 4096l * 2048;   // qk per-dir elems (16 MB)
  const long sVT = 4096l * 1024;   // vt per-dir elems (8 MB)
  const long sY  = 4096l * 1024;   // y per-dir elems (8 MB)

  if (batched) {
    bf16_t* x_c    = (bf16_t*)(ws);              // 8 MB   -> wout_c later
    bf16_t* wq_c   = (bf16_t*)(ws + 8 * MB);     // 24 MB
    bf16_t* wo_c   = (bf16_t*)(ws + 32 * MB);    // 8 MB
    bf16_t* qk     = (bf16_t*)(ws + 40 * MB);    // 64 MB (4 dirs, pos order)
    bf16_t* vt     = (bf16_t*)(ws + 104 * MB);   // 32 MB (4 dirs, [b][h][d][p])
    bf16_t* y      = (bf16_t*)(ws + 136 * MB);   // 32 MB -> gated
    bf16_t* concat = (bf16_t*)(ws + 40 * MB);    // 32 MB (phase 2, qk dirs 0-1 dead)
    bf16_t* wg_c   = (bf16_t*)(ws + 72 * MB);    // 32 MB (qk dirs 2-3 dead)
    bf16_t* wout_c = (bf16_t*)(ws);              // 8 MB (x dead)
    float*  part4  = (float*)(ws + 40 * MB);     // 64 MB (concat+wg dead after gate)
    bf16_t* gated  = y;

    {  // convert x, wqkv x4, wo x4
      CvtDesc cd;
      cd.src[0] = xf; cd.dst[0] = x_c; cd.n8[0] = 4194304 / 8;
      for (int d = 0; d < 4; d++) {
        cd.src[1 + d] = wqkv_f[d];
        cd.dst[1 + d] = wq_c + (long)d * 3145728;
        cd.n8[1 + d] = 3145728 / 8;
        cd.src[5 + d] = wo_f[d];
        cd.dst[5 + d] = wo_c + (long)d * 1048576;
        cd.n8[5 + d] = 1048576 / 8;
      }
      cvt9_k<<<dim3(2048, 9), blk, 0, stream>>>(cd);
    }
    {  // qkv GEMM (256^2 8-phase), 4 dirs: Q,K -> pos order; V -> vt transposed
      Ptr4 bq{{wq_c, wq_c + 3145728, wq_c + 2l * 3145728, wq_c + 3l * 3145728}};
      gemm_bt2<4><<<dim3(12, 16, 4), blk2, 0, stream>>>(
          x_c, 0, 1024, bq, 1024, qk, sQK, 2048, 1024, 0, nullptr, nullptr,
          vt, sVT, 0);
    }
    attn_k<<<dim3(3, 256), blk, 0, stream>>>(qk, sQK, vt, sVT, y, sY, 0);
    {  // convert wgate + wout (after attn: overlays qk/x space)
      CvtDesc cd;
      for (int s = 0; s < 9; s++) cd.n8[s] = 0;
      cd.src[0] = wgate_f; cd.dst[0] = wg_c; cd.n8[0] = 16777216 / 8;
      cd.src[1] = wout_f; cd.dst[1] = wout_c; cd.n8[1] = 4194304 / 8;
      cvt9_k<<<dim3(8192, 2), blk, 0, stream>>>(cd);
    }
    {  // out-proj, z-batched -> concat[:, z*1024:(z+1)*1024]  (256^2 8-phase)
      Ptr4 b4{{wo_c, wo_c + 1048576, wo_c + 2097152, wo_c + 3145728}};
      gemm_bt2<0><<<dim3(4, 16, 4), blk2, 0, stream>>>(
          y, sY, 1024, b4, 1024, concat, 1024, 4096, 1024, 0, nullptr, nullptr,
          nullptr, 0, 0);
    }
    {  // gated = sigmoid(concat@wg^T + b) * concat  (256^2 8-phase)
      Ptr4 b4{{wg_c, wg_c, wg_c, wg_c}};
      gemm_bt2<1><<<dim3(16, 16, 1), blk2, 0, stream>>>(
          concat, 0, 4096, b4, 4096, gated, 0, 4096, 4096, 0, bgate_f, concat,
          nullptr, 0, 0);
    }
    {  // split-K=4 w_out partials into part4 (concat/wg region, now dead)
      Ptr4 b4{{wout_c, wout_c, wout_c, wout_c}};
      gemm_bt2<3><<<dim3(4, 16, 4), blk2, 0, stream>>>(
          gated, 0, 4096, b4, 4096, part4, (long)4096 * 1024, 1024, 1024, 1024,
          nullptr, nullptr, nullptr, 0, 0);
    }
    rmsnorm_k<<<dim3(4096), blk, 0, stream>>>(
        part4, part4 + (long)4096 * 1024, part4 + 2l * 4096 * 1024,
        part4 + 3l * 4096 * 1024, xf, normw_f, (float*)d_out);
  } else {
    // fallback (96 MB): per-dir qkv+attn, legacy 128^2 GEMMs
    bf16_t* x_c    = (bf16_t*)(ws);              // 8 MB
    bf16_t* wq_c   = (bf16_t*)(ws + 8 * MB);     // 24 MB
    bf16_t* qk_d   = (bf16_t*)(ws + 32 * MB);    // 16 MB (per-dir)
    bf16_t* vt_d   = (bf16_t*)(ws + 48 * MB);    // 8 MB (per-dir)
    bf16_t* wo_c   = (bf16_t*)(ws + 56 * MB);    // 8 MB
    bf16_t* y      = (bf16_t*)(ws + 64 * MB);    // 32 MB -> gated
    bf16_t* concat = (bf16_t*)(ws);              // 32 MB (phase 2)
    bf16_t* wg_c   = (bf16_t*)(ws + 32 * MB);    // 32 MB (after out-proj)
    bf16_t* wout_c = (bf16_t*)(ws);              // 8 MB (after gate)
    float*  part   = (float*)(ws + 8 * MB);      // 32 MB
    bf16_t* gated  = y;

    {
      CvtDesc cd;
      cd.src[0] = xf; cd.dst[0] = x_c; cd.n8[0] = 4194304 / 8;
      for (int d = 0; d < 4; d++) {
        cd.src[1 + d] = wqkv_f[d];
        cd.dst[1 + d] = wq_c + (long)d * 3145728;
        cd.n8[1 + d] = 3145728 / 8;
        cd.src[5 + d] = wo_f[d];
        cd.dst[5 + d] = wo_c + (long)d * 1048576;
        cd.n8[5 + d] = 1048576 / 8;
      }
      cvt9_k<<<dim3(2048, 9), blk, 0, stream>>>(cd);
    }
    for (int d = 0; d < 4; d++) {
      const bf16_t* wq_d = wq_c + (long)d * 3145728;
      Ptr4 bq{{wq_d, wq_d, wq_d, wq_d}};
      gemm_bt<4><<<dim3(24, 32, 1), blk, 0, stream>>>(
          x_c, 0, 1024, bq, 1024, qk_d, 0, 2048, 1024, 0, nullptr, nullptr,
          vt_d, 0, d);
      attn_k<<<dim3(3, 64), blk, 0, stream>>>(qk_d, 0, vt_d, 0,
                                              y + (long)d * sY, 0, d);
    }
    {
      Ptr4 b4{{wo_c, wo_c + 1048576, wo_c + 2097152, wo_c + 3145728}};
      gemm_bt<0><<<dim3(8, 32, 4), blk, 0, stream>>>(
          y, sY, 1024, b4, 1024, concat, 1024, 4096, 1024, 0, nullptr, nullptr,
          nullptr, 0, 0);
    }
    {
      CvtDesc cd;
      for (int s = 0; s < 9; s++) cd.n8[s] = 0;
      cd.src[0] = wgate_f; cd.dst[0] = wg_c; cd.n8[0] = 16777216 / 8;
      cvt9_k<<<dim3(8192, 1), blk, 0, stream>>>(cd);
    }
    {
      Ptr4 b4{{wg_c, wg_c, wg_c, wg_c}};
      gemm_bt<1><<<dim3(32, 32, 1), blk, 0, stream>>>(
          concat, 0, 4096, b4, 4096, gated, 0, 4096, 4096, 0, bgate_f, concat,
          nullptr, 0, 0);
    }
    {
      CvtDesc cd;
      for (int s = 0; s < 9; s++) cd.n8[s] = 0;
      cd.src[0] = wout_f; cd.dst[0] = wout_c; cd.n8[0] = 4194304 / 8;
      cvt9_k<<<dim3(2048, 1), blk, 0, stream>>>(cd);
    }
    {
      Ptr4 b4{{wout_c, wout_c, wout_c, wout_c}};
      gemm_bt<3><<<dim3(8, 32, 2), blk, 0, stream>>>(
          gated, 0, 4096, b4, 4096, part, (long)4096 * 1024, 1024, 2048, 2048,
          nullptr, nullptr, nullptr, 0, 0);
    }
    rmsnorm_k<<<dim3(4096), blk, 0, stream>>>(part, part + (long)4096 * 1024,
                                              nullptr, nullptr,
                                              xf, normw_f, (float*)d_out);
  }
}

// Round 6
// 605.938 us; speedup vs baseline: 1.1959x; 1.0728x over previous
//
#include <hip/hip_runtime.h>
#include <hip/hip_bf16.h>
#include <math.h>

// ---------------------------------------------------------------------------
// MultiDirectionalGridAttention. FP32 in/out; bf16 MFMA core, fp32 accum.
// B=4, T=1024 (32x32 grid), D=1024, NH=16, hd=64.
//
// R14 = R13 + coalesced V-transpose store for dirs 2/3 in gemm_bt2 MODE 4.
// Old: scalar 2B scatter at stride-32 positions -> ~2x HBM write
// amplification (WRITE_SIZE 200MB vs 96MB payload) + 128 scalar global
// stores/thread. New: pos-compressed bf16 LDS bounce sV[128][264] (2 passes
// of 128 channels): writer puts acc at cpi=(u&31)*8+((u>>5)&7) (u = dir-
// reflected token); reader ds_read_b128's 8 consecutive cpi = 8 consecutive
// POSITIONS and stores 16B contiguous -> full line utilization.
// Keeps (R13): attn 3-way uniform q-tile grouping (768 blocks = 3/CU,
// launch_bounds(256,3)), K pre-scaled 0.125, boundary-only mask,
// defer-rescale, 8-phase gemm_bt2 everywhere.
//
// Batched ws (168 MB): [0,8)x_c->wout_c  [8,32)wq_c  [32,40)wo_c
//   [40,104) qk 4x16MB (pos-order [Q|K], ldc 2048) -> concat[40,72), wg[72,104)
//       -> part4 [40,104) (4x16MB, after gate)
//   [104,136) vt 4x8MB  [136,168) y->gated
// ---------------------------------------------------------------------------

typedef __bf16 bf16_t;
typedef __bf16 bf16x4 __attribute__((ext_vector_type(4)));
typedef __bf16 bf16x8 __attribute__((ext_vector_type(8)));
typedef float  f32x4  __attribute__((ext_vector_type(4)));

#define MFMA16(a, b, c) __builtin_amdgcn_mfma_f32_16x16x32_bf16((a), (b), (c), 0, 0, 0)

__device__ __forceinline__ void async16(const bf16_t* g, bf16_t* l) {
  __builtin_amdgcn_global_load_lds((const __attribute__((address_space(1))) void*)g,
                                   (__attribute__((address_space(3))) void*)l,
                                   16, 0, 0);
}

// 16-lane (DPP row) all-reduce: xor1, xor2 quad-perms then row_ror:4, row_ror:8.
__device__ __forceinline__ float dpp_max16(float x) {
  float t;
  t = __builtin_bit_cast(float, __builtin_amdgcn_update_dpp(0, __builtin_bit_cast(int, x), 0xB1, 0xF, 0xF, true));
  x = fmaxf(x, t);
  t = __builtin_bit_cast(float, __builtin_amdgcn_update_dpp(0, __builtin_bit_cast(int, x), 0x4E, 0xF, 0xF, true));
  x = fmaxf(x, t);
  t = __builtin_bit_cast(float, __builtin_amdgcn_update_dpp(0, __builtin_bit_cast(int, x), 0x124, 0xF, 0xF, true));
  x = fmaxf(x, t);
  t = __builtin_bit_cast(float, __builtin_amdgcn_update_dpp(0, __builtin_bit_cast(int, x), 0x128, 0xF, 0xF, true));
  x = fmaxf(x, t);
  return x;
}
__device__ __forceinline__ float dpp_sum16(float x) {
  float t;
  t = __builtin_bit_cast(float, __builtin_amdgcn_update_dpp(0, __builtin_bit_cast(int, x), 0xB1, 0xF, 0xF, true));
  x += t;
  t = __builtin_bit_cast(float, __builtin_amdgcn_update_dpp(0, __builtin_bit_cast(int, x), 0x4E, 0xF, 0xF, true));
  x += t;
  t = __builtin_bit_cast(float, __builtin_amdgcn_update_dpp(0, __builtin_bit_cast(int, x), 0x124, 0xF, 0xF, true));
  x += t;
  t = __builtin_bit_cast(float, __builtin_amdgcn_update_dpp(0, __builtin_bit_cast(int, x), 0x128, 0xF, 0xF, true));
  x += t;
  return x;
}

struct Ptr4 { const bf16_t* p[4]; };

// Causal-order position p <-> token t (involution).
__device__ __forceinline__ int perm_t(int p, int dir) {
  int q = (dir & 1) ? (1023 - p) : p;
  if (dir >= 2) q = ((q & 31) << 5) | (q >> 5);
  return q;
}

// ------------------- batched fp32 -> bf16 convert (<=9 segments) ------------
struct CvtDesc {
  const float* src[9];
  bf16_t* dst[9];
  int n8[9];
};

__device__ __forceinline__ void cvt8(const float* in, bf16_t* out, int i) {
  const float4 a = ((const float4*)in)[i * 2];
  const float4 b = ((const float4*)in)[i * 2 + 1];
  bf16x8 o;
  o[0] = (bf16_t)a.x; o[1] = (bf16_t)a.y; o[2] = (bf16_t)a.z; o[3] = (bf16_t)a.w;
  o[4] = (bf16_t)b.x; o[5] = (bf16_t)b.y; o[6] = (bf16_t)b.z; o[7] = (bf16_t)b.w;
  ((bf16x8*)out)[i] = o;
}

__global__ __launch_bounds__(256) void cvt9_k(CvtDesc d) {
  const int seg = blockIdx.y;
  const int i = blockIdx.x * 256 + threadIdx.x;
  if (i >= d.n8[seg]) return;
  cvt8(d.src[seg], d.dst[seg], i);
}

// ---------------------------------------------------------------------------
// gemm_bt2: C = A * B^T, bf16 in, fp32 acc. 256x256 tile, BK=64, 512 threads,
// 8 waves (2M x 4N), each wave owns 128x64 output (acc[8][4] f32x4).
// Double-buffered 128 KiB LDS; per K-tile 4 phases of
//   {ds_read frags ; stage half-tile ; s_barrier ; lgkmcnt(0) ;
//    setprio(1) ; 16 MFMA ; setprio(0) ; s_barrier}
// Prefetch loads for tile kt+1 issued in phases 0-1 of kt; end-of-tile
// vmcnt(0) folded into phase-3's trailing barrier. LDS rows 128B, 16B-block
// XOR swizzle blk' = blk ^ (row&7) (both-sides).
// MODE 0: bf16 C.  MODE 1: sigmoid-gate vs gin.  MODE 3: fp32 split-K part.
// MODE 4: qkv. K block (bn in [1024,2048)) pre-scaled by 0.125. V blocks:
//   dirs 0/1 transposed f32 bounce + contiguous (reversed) stores; dirs 2/3
//   pos-compressed bf16 bounce -> 16B contiguous stores.
// ---------------------------------------------------------------------------
template <int MODE>
__global__ __launch_bounds__(512, 2) void gemm_bt2(
    const bf16_t* __restrict__ A, long sAz, int lda,
    Ptr4 B4, int ldb,
    void* __restrict__ Cv, long sCz, int ldc, int K, int koff,
    const float* __restrict__ bias,
    const bf16_t* __restrict__ gin,
    bf16_t* __restrict__ vtp, long sVz, int dirbase) {
  constexpr int BM = 256, BN = 256, BK = 64;
  (void)BM; (void)BN;
  __shared__ __align__(16) char smem[131072];

  const int z = blockIdx.z;
  const bf16_t* Ap = A + (long)z * sAz;
  const bf16_t* Bp = B4.p[z];
  const int tid = threadIdx.x;
  const int lane = tid & 63;
  const int wave = tid >> 6;
  const int l15 = lane & 15, qd = lane >> 4;
  const int wm = wave >> 2, wn = wave & 3;  // 2 x 4 wave grid
  const int bm = blockIdx.y * 256, bn = blockIdx.x * 256;
  const int kz = (MODE == 3) ? z * koff : 0;
  const int NT = K / BK;

  // ---- staging thread-constants (pre-swizzled global source) ----
  const int row0 = tid >> 3;                          // 0..63
  const int blkp = ((tid & 7) ^ (row0 & 7)) * 8;      // swizzled 16B block (elems)
  const bf16_t* gA = Ap + (long)(bm + row0) * lda + blkp + kz;
  const bf16_t* gB = Bp + (long)(bn + row0) * ldb + blkp + kz;
  char* const sm = (char*)smem;
  const int ldsT = tid * 16;                          // lane-linear dest

  // ---- fragment read bases (byte offsets inside one buffer) ----
  const int xorv = (l15 & 7) << 4;
  const int aBase = (wm * 128 + l15) * 128;           // A region [0, 32KB)
  const int bBase = 32768 + (wn * 64 + l15) * 128;    // B region [32KB, 64KB)
  const int colk0 = (qd * 16) ^ xorv;
  const int colk1 = (64 + qd * 16) ^ xorv;

  f32x4 acc[8][4];
#pragma unroll
  for (int i = 0; i < 8; i++)
#pragma unroll
    for (int j = 0; j < 4; j++) acc[i][j] = (f32x4){0.f, 0.f, 0.f, 0.f};

  // ---- prologue: stage tile 0 into buf 0 ----
#pragma unroll
  for (int u = 0; u < 4; u++)
    async16(gA + (long)(u * 64) * lda, (bf16_t*)(sm + u * 8192 + ldsT));
#pragma unroll
  for (int u = 0; u < 4; u++)
    async16(gB + (long)(u * 64) * ldb, (bf16_t*)(sm + 32768 + u * 8192 + ldsT));
  asm volatile("s_waitcnt vmcnt(0)" ::: "memory");
  __builtin_amdgcn_s_barrier();

  for (int kt = 0; kt < NT; ++kt) {
    const int c = kt & 1;
    const char* sa = sm + c * 65536;
    const int nb = (c ^ 1) * 65536;
    const long ko = (long)(kt + 1) * BK;
    bf16x8 bF[4][2];
#pragma unroll
    for (int p = 0; p < 4; ++p) {
      // -- ds-read this phase's fragments --
      if (p == 0) {
#pragma unroll
        for (int n = 0; n < 4; ++n) {
          bF[n][0] = *(const bf16x8*)(sa + bBase + n * 2048 + colk0);
          bF[n][1] = *(const bf16x8*)(sa + bBase + n * 2048 + colk1);
        }
      }
      bf16x8 aF[2][2];
#pragma unroll
      for (int mm = 0; mm < 2; ++mm) {
        aF[mm][0] = *(const bf16x8*)(sa + aBase + (p * 2 + mm) * 2048 + colk0);
        aF[mm][1] = *(const bf16x8*)(sa + aBase + (p * 2 + mm) * 2048 + colk1);
      }
      // -- stage next tile (A halves in phase 0, B halves in phase 1) --
      if (kt + 1 < NT) {
        if (p == 0) {
#pragma unroll
          for (int u = 0; u < 4; u++)
            async16(gA + (long)(u * 64) * lda + ko,
                    (bf16_t*)(sm + nb + u * 8192 + ldsT));
        } else if (p == 1) {
#pragma unroll
          for (int u = 0; u < 4; u++)
            async16(gB + (long)(u * 64) * ldb + ko,
                    (bf16_t*)(sm + nb + 32768 + u * 8192 + ldsT));
        }
      }
      __builtin_amdgcn_s_barrier();
      asm volatile("s_waitcnt lgkmcnt(0)" ::: "memory");
      __builtin_amdgcn_s_setprio(1);
#pragma unroll
      for (int kh = 0; kh < 2; ++kh)
#pragma unroll
        for (int mm = 0; mm < 2; ++mm)
#pragma unroll
          for (int n = 0; n < 4; ++n)
            acc[p * 2 + mm][n] =
                MFMA16(aF[mm][kh], bF[n][kh], acc[p * 2 + mm][n]);
      __builtin_amdgcn_s_setprio(0);
      if (p == 3 && kt + 1 < NT)  // next tile resident before its phase-0 reads
        asm volatile("s_waitcnt vmcnt(0)" ::: "memory");
      __builtin_amdgcn_s_barrier();
    }
  }

  // ---- epilogue ----
  if constexpr (MODE == 4) {
    const int dir = dirbase + z;
    if (bn < 2048) {  // Q,K: MODE-0-style bounce, row-permuted coalesced store
      bf16_t* qkz = (bf16_t*)Cv + (long)z * sCz;
      const float ksc = (bn >= 1024) ? 0.125f : 1.0f;  // pre-scale K by 1/8
      float* sC = (float*)smem;
#pragma unroll
      for (int p = 0; p < 4; ++p) {
        if (p) __syncthreads();
        if (wm == (p >> 1)) {
#pragma unroll
          for (int mm = 0; mm < 4; ++mm) {
            const int m = (p & 1) * 4 + mm;
#pragma unroll
            for (int n = 0; n < 4; ++n)
#pragma unroll
              for (int r = 0; r < 4; ++r)
                sC[(mm * 16 + qd * 4 + r) * 260 + wn * 64 + n * 16 + l15] =
                    acc[m][n][r];
          }
        }
        __syncthreads();
#pragma unroll
        for (int i = 0; i < 8; ++i) {
          const int idx = i * 512 + tid;
          const int rl = idx >> 6, c4 = (idx & 63) * 4;
          const float4 v4 = *(const float4*)&sC[rl * 260 + c4];
          const int grow = bm + p * 64 + rl;
          const int prow = (grow & ~1023) | perm_t(grow & 1023, dir);
          bf16x4 o;
          o[0] = (bf16_t)(v4.x * ksc); o[1] = (bf16_t)(v4.y * ksc);
          o[2] = (bf16_t)(v4.z * ksc); o[3] = (bf16_t)(v4.w * ksc);
          *(bf16x4*)(qkz + (long)prow * ldc + bn + c4) = o;
        }
      }
    } else if (dir < 2) {  // V dirs 0/1: transposed f32 bounce, contiguous
      bf16_t* vz = vtp + (long)z * sVz;
      float* sCt = (float*)smem;
#pragma unroll
      for (int p = 0; p < 4; ++p) {
        if (p) __syncthreads();
        if (wm == (p >> 1)) {
#pragma unroll
          for (int mm = 0; mm < 4; ++mm) {
            const int m = (p & 1) * 4 + mm;
#pragma unroll
            for (int n = 0; n < 4; ++n)
#pragma unroll
              for (int r = 0; r < 4; ++r)
                sCt[(wn * 64 + n * 16 + l15) * 68 + mm * 16 + qd * 4 + r] =
                    acc[m][n][r];
          }
        }
        __syncthreads();
#pragma unroll
        for (int i = 0; i < 8; ++i) {
          const int idx = i * 512 + tid;         // 4096 = 256 cols x 16 chunks
          const int col = idx >> 4, tq = idx & 15;
          const float4 v4 = *(const float4*)&sCt[col * 68 + tq * 4];
          const int t0 = (bm & 1023) + p * 64 + tq * 4;
          const int bb = bm >> 10;
          const int ch = bn + col - 2048;
          bf16_t* vrow =
              vz + (((long)bb * 16 + (ch >> 6)) * 64 + (ch & 63)) * 1024;
          if (dir == 0) {
            bf16x4 o;
            o[0] = (bf16_t)v4.x; o[1] = (bf16_t)v4.y;
            o[2] = (bf16_t)v4.z; o[3] = (bf16_t)v4.w;
            *(bf16x4*)(vrow + t0) = o;
          } else {
            bf16x4 o;
            o[0] = (bf16_t)v4.w; o[1] = (bf16_t)v4.z;
            o[2] = (bf16_t)v4.y; o[3] = (bf16_t)v4.x;
            *(bf16x4*)(vrow + (1020 - t0)) = o;
          }
        }
      }
    } else {  // V dirs 2/3: pos-compressed bf16 bounce -> 16B contiguous stores
      // pos = (u&31)*32 + (u>>5), u = dir-reflected token; within the block's
      // 256 tokens, u>>5 spans 8 aligned values -> cpi = (u&31)*8 + ((u>>5)&7)
      // compresses to 32 runs of 8 CONSECUTIVE positions.
      bf16_t* vz = vtp + (long)z * sVz;
      bf16_t* sV = (bf16_t*)smem;               // [128 ch][264] bf16 (67.6 KB)
      const int bmm = bm & 1023;
      const int bb = bm >> 10;
      const int ub5 = ((dir & 1) ? (768 - bmm) : bmm) >> 5;  // multiple of 8
#pragma unroll
      for (int h = 0; h < 2; ++h) {
        if (h) __syncthreads();
        if ((wn >> 1) == h) {
          const int colB = (wn & 1) * 64;
#pragma unroll
          for (int m = 0; m < 8; ++m)
#pragma unroll
            for (int n = 0; n < 4; ++n)
#pragma unroll
              for (int r = 0; r < 4; ++r) {
                const int t = bmm + wm * 128 + m * 16 + qd * 4 + r;
                const int u = (dir & 1) ? (1023 - t) : t;
                const int cpi = (u & 31) * 8 + ((u >> 5) & 7);
                sV[(colB + n * 16 + l15) * 264 + cpi] = (bf16_t)acc[m][n][r];
              }
        }
        __syncthreads();
#pragma unroll
        for (int i = 0; i < 8; ++i) {
          const int idx = i * 512 + tid;        // 4096 = 128 cols x 32 cgroups
          const int col = idx >> 5, cg = idx & 31;
          const bf16x8 v = *(const bf16x8*)&sV[col * 264 + cg * 8];
          const int ch = bn + h * 128 + col - 2048;
          bf16_t* vrow =
              vz + (((long)bb * 16 + (ch >> 6)) * 64 + (ch & 63)) * 1024;
          *(bf16x8*)(vrow + cg * 32 + ub5) = v;
        }
      }
    }
  } else {
    float* sC = (float*)smem;
#pragma unroll
    for (int p = 0; p < 4; ++p) {
      if (p) __syncthreads();
      if (wm == (p >> 1)) {
#pragma unroll
        for (int mm = 0; mm < 4; ++mm) {
          const int m = (p & 1) * 4 + mm;
#pragma unroll
          for (int n = 0; n < 4; ++n)
#pragma unroll
            for (int r = 0; r < 4; ++r)
              sC[(mm * 16 + qd * 4 + r) * 260 + wn * 64 + n * 16 + l15] =
                  acc[m][n][r];
        }
      }
      __syncthreads();
#pragma unroll
      for (int i = 0; i < 8; ++i) {
        const int idx = i * 512 + tid;
        const int rl = idx >> 6, c4 = (idx & 63) * 4;
        const float4 v4 = *(const float4*)&sC[rl * 260 + c4];
        const int grow = bm + p * 64 + rl;
        const int gcol = bn + c4;
        const long goff = (long)grow * ldc + gcol;
        if constexpr (MODE == 0) {
          bf16x4 o;
          o[0] = (bf16_t)v4.x; o[1] = (bf16_t)v4.y;
          o[2] = (bf16_t)v4.z; o[3] = (bf16_t)v4.w;
          *(bf16x4*)((bf16_t*)Cv + (long)z * sCz + goff) = o;
        } else if constexpr (MODE == 1) {
          const float4 bb = *(const float4*)&bias[gcol];
          const bf16x4 gv = *(const bf16x4*)&gin[goff];
          bf16x4 o;
          o[0] = (bf16_t)((float)gv[0] / (1.f + __expf(-(v4.x + bb.x))));
          o[1] = (bf16_t)((float)gv[1] / (1.f + __expf(-(v4.y + bb.y))));
          o[2] = (bf16_t)((float)gv[2] / (1.f + __expf(-(v4.z + bb.z))));
          o[3] = (bf16_t)((float)gv[3] / (1.f + __expf(-(v4.w + bb.w))));
          *(bf16x4*)((bf16_t*)Cv + goff) = o;
        } else {
          *(float4*)((float*)Cv + (long)z * sCz + goff) = v4;
        }
      }
    }
  }
}

// ---------------------------------------------------------------------------
// Legacy 128x128 gemm (m97 structure) — retained for the low-ws fallback path.
// ---------------------------------------------------------------------------
template <int MODE>
__global__ __launch_bounds__(256) void gemm_bt(
    const bf16_t* __restrict__ A, long sAz, int lda,
    Ptr4 B4, int ldb,
    void* __restrict__ Cv, long sCz, int ldc, int K, int koff,
    const float* __restrict__ bias,
    const bf16_t* __restrict__ gin,
    bf16_t* __restrict__ vtp, long sVz, int dirbase) {
  constexpr int BM = 128, BN = 128, BK = 32;
  __shared__ __align__(16) char smem[18432];
  bf16_t* sA = (bf16_t*)smem;
  bf16_t* sB = (bf16_t*)(smem + BM * BK * 2);
  float* sC = (float*)smem;

  const int z = blockIdx.z;
  const bf16_t* Ap = A + (long)z * sAz;
  const bf16_t* Bp = B4.p[z];
  const int tid = threadIdx.x;
  const int wave = tid >> 6, lane = tid & 63;
  const int lane15 = lane & 15, quad = lane >> 4;
  const int bm = blockIdx.y * BM, bn = blockIdx.x * BN;
  const int wm = (wave >> 1) * 64, wn = (wave & 1) * 64;

  f32x4 acc[4][4];
#pragma unroll
  for (int i = 0; i < 4; i++)
#pragma unroll
    for (int j = 0; j < 4; j++) acc[i][j] = (f32x4){0.f, 0.f, 0.f, 0.f};

  const int srow = wave * 16 + (lane >> 2);
  const int skoff = (lane & 3) * 8;
  const int kz = (MODE == 3) ? z * koff : 0;
  const bf16_t* ga = Ap + (long)(bm + srow) * lda + skoff + kz;
  const bf16_t* gb = Bp + (long)(bn + srow) * ldb + skoff + kz;
  bf16_t* la = &sA[srow * BK + skoff];
  bf16_t* lb = &sB[srow * BK + skoff];

  for (int k0 = 0; k0 < K; k0 += BK) {
    __syncthreads();
    async16(ga + k0, la);
    async16(ga + k0 + (long)64 * lda, la + 64 * BK);
    async16(gb + k0, lb);
    async16(gb + k0 + (long)64 * ldb, lb + 64 * BK);
    __syncthreads();

    bf16x8 af[4], bfv[4];
#pragma unroll
    for (int i = 0; i < 4; i++)
      af[i] = *(const bf16x8*)&sA[(wm + i * 16 + lane15) * BK + quad * 8];
#pragma unroll
    for (int j = 0; j < 4; j++)
      bfv[j] = *(const bf16x8*)&sB[(wn + j * 16 + lane15) * BK + quad * 8];
#pragma unroll
    for (int i = 0; i < 4; i++)
#pragma unroll
      for (int j = 0; j < 4; j++)
        acc[i][j] = MFMA16(af[i], bfv[j], acc[i][j]);
  }

  __syncthreads();  // all waves done reading sA/sB before the sC overlay

  // ------------- epilogue -------------
  if constexpr (MODE == 4) {
    const int dir = dirbase + z;
    if (bn < 2048) {  // Q,K: 4 passes of 16+16 rows, row-permuted store
      bf16_t* qkz = (bf16_t*)Cv + (long)z * sCz;
      const float ksc = (bn >= 1024) ? 0.125f : 1.0f;  // pre-scale K by 1/8
#pragma unroll
      for (int p = 0; p < 4; p++) {
        if (p) __syncthreads();
        const int sr = (wm >> 2) + quad * 4;  // wm=0 -> 0..15, wm=64 -> 16..31
#pragma unroll
        for (int r = 0; r < 4; r++)
#pragma unroll
          for (int j = 0; j < 4; j++)
            sC[(sr + r) * 144 + wn + j * 16 + lane15] = acc[p][j][r];
        __syncthreads();
#pragma unroll
        for (int c = 0; c < 4; c++) {
          const int idx = c * 256 + tid;
          const int srr = idx >> 5, chunk = idx & 31;
          const float4 v4 = *(const float4*)&sC[srr * 144 + chunk * 4];
          const int grow = bm + p * 16 + (srr & 15) + (srr >> 4) * 64;
          const int prow = (grow & ~1023) | perm_t(grow & 1023, dir);
          bf16x4 o;
          o[0] = (bf16_t)(v4.x * ksc); o[1] = (bf16_t)(v4.y * ksc);
          o[2] = (bf16_t)(v4.z * ksc); o[3] = (bf16_t)(v4.w * ksc);
          *(bf16x4*)(qkz + (long)prow * 2048 + bn + chunk * 4) = o;
        }
      }
    } else {  // V: 4 passes (row-half p x col-half q) -> vt[b][h][d][pos]
      bf16_t* vz = vtp + (long)z * sVz;
      float* sCt = sC;  // [col 0..63][tok-compressed 0..63], stride 68
#pragma unroll
      for (int p = 0; p < 2; p++)
#pragma unroll
        for (int q = 0; q < 2; q++) {
          if (p || q) __syncthreads();
          if ((wave & 1) == q) {  // only waves with wn == 64q hold these cols
#pragma unroll
            for (int ii = 0; ii < 2; ii++) {
              const int i = 2 * p + ii;
              const int srb = (wm >> 1) + ii * 16 + quad * 4;
#pragma unroll
              for (int r = 0; r < 4; r++)
#pragma unroll
                for (int j = 0; j < 4; j++)
                  sCt[(j * 16 + lane15) * 68 + srb + r] = acc[i][j][r];
            }
          }
          __syncthreads();
#pragma unroll
          for (int c = 0; c < 4; c++) {
            const int idx = c * 256 + tid;
            const int col = idx >> 4, tq = idx & 15;
            const int srr0 = (tq & 7) * 4 + (tq >> 3) * 32;
            const float4 v4 = *(const float4*)&sCt[col * 68 + srr0];
            const int t0 = (bm & 1023) + p * 32 + (srr0 & 31) + (srr0 >> 5) * 64;
            const int bb = bm >> 10;
            const int ch = bn + 64 * q + col - 2048;
            bf16_t* vrow =
                vz + (((long)bb * 16 + (ch >> 6)) * 64 + (ch & 63)) * 1024;
            if (dir == 0) {
              bf16x4 o;
              o[0] = (bf16_t)v4.x; o[1] = (bf16_t)v4.y;
              o[2] = (bf16_t)v4.z; o[3] = (bf16_t)v4.w;
              *(bf16x4*)(vrow + t0) = o;
            } else if (dir == 1) {
              bf16x4 o;
              o[0] = (bf16_t)v4.w; o[1] = (bf16_t)v4.z;
              o[2] = (bf16_t)v4.y; o[3] = (bf16_t)v4.x;
              *(bf16x4*)(vrow + (1020 - t0)) = o;
            } else {
              vrow[perm_t(t0 + 0, dir)] = (bf16_t)v4.x;
              vrow[perm_t(t0 + 1, dir)] = (bf16_t)v4.y;
              vrow[perm_t(t0 + 2, dir)] = (bf16_t)v4.z;
              vrow[perm_t(t0 + 3, dir)] = (bf16_t)v4.w;
            }
          }
        }
    }
  } else {
#pragma unroll
    for (int p = 0; p < 4; p++) {
      if (p) __syncthreads();
      const int sr = (wm >> 2) + quad * 4;
#pragma unroll
      for (int r = 0; r < 4; r++)
#pragma unroll
        for (int j = 0; j < 4; j++)
          sC[(sr + r) * 144 + wn + j * 16 + lane15] = acc[p][j][r];
      __syncthreads();
#pragma unroll
      for (int c = 0; c < 4; c++) {
        const int idx = c * 256 + tid;
        const int srr = idx >> 5, chunk = idx & 31;
        const float4 v4 = *(const float4*)&sC[srr * 144 + chunk * 4];
        const int grow = bm + p * 16 + (srr & 15) + (srr >> 4) * 64;
        const int gcol = bn + chunk * 4;
        const long goff = (long)grow * ldc + gcol;
        if constexpr (MODE == 0) {
          bf16x4 o;
          o[0] = (bf16_t)v4.x; o[1] = (bf16_t)v4.y;
          o[2] = (bf16_t)v4.z; o[3] = (bf16_t)v4.w;
          *(bf16x4*)((bf16_t*)Cv + (long)z * sCz + goff) = o;
        } else if constexpr (MODE == 1) {
          const float4 bb = *(const float4*)&bias[gcol];
          const bf16x4 gv = *(const bf16x4*)&gin[goff];
          bf16x4 o;
          o[0] = (bf16_t)((float)gv[0] / (1.f + __expf(-(v4.x + bb.x))));
          o[1] = (bf16_t)((float)gv[1] / (1.f + __expf(-(v4.y + bb.y))));
          o[2] = (bf16_t)((float)gv[2] / (1.f + __expf(-(v4.z + bb.z))));
          o[3] = (bf16_t)((float)gv[3] / (1.f + __expf(-(v4.w + bb.w))));
          *(bf16x4*)((bf16_t*)Cv + goff) = o;
        } else {
          *(float4*)((float*)Cv + (long)z * sCz + goff) = v4;
        }
      }
    }
  }
}

// ---------------------------------------------------------------------------
// Flash attention, pure-causal in position space (no perm in hot loop).
// Block = 4 waves x 32 q-rows; grid (3, Ybh) = 3 blocks per (dir,b,h), each
// running a uniform 24 k-tile-units of q-tiles: bx=0 -> {7,3}, bx=1 -> {6,4},
// bx=2 -> {5,2,1,0}. 768 blocks = exactly 3/CU at launch_bounds(256,3).
// XCD swizzle (768 % 8 == 0, bijective) keeps one (dir,b,h)'s blocks on one
// XCD. K pre-scaled by 0.125; mask on boundary tiles only; defer-rescale.
// ---------------------------------------------------------------------------
__global__ __launch_bounds__(256, 3) void attn_k(
    const bf16_t* __restrict__ qk, long sQz,
    const bf16_t* __restrict__ vt, long sVz,
    bf16_t* __restrict__ y, long sYz, int dir0) {
  const int p0 = blockIdx.y * 3 + blockIdx.x;
  const int chunk = (gridDim.y * 3) >> 3;        // blocks per XCD
  const int lg = (p0 & 7) * chunk + (p0 >> 3);
  const int bx = lg % 3, by = lg / 3;
  const int zi = by >> 6;
  const int bh = by & 63;
  const int dir = dir0 + zi;
  const int b = bh >> 4, h = bh & 15;
  const int tid = threadIdx.x;
  const int wave = tid >> 6, lane = tid & 63;
  const int lane15 = lane & 15, quad = lane >> 4;
  const int hoff = h * 64;
  const bf16_t* base = qk + (long)zi * sQz + (long)b * 1024 * 2048;
  const bf16_t* vth = vt + (long)zi * sVz + ((long)b * 16 + h) * 64 * 1024;
  bf16_t* yd = y + (long)zi * sYz;

  __shared__ __align__(16) bf16_t sK[64 * 72];
  __shared__ __align__(16) bf16_t sVt[64 * 72];
  __shared__ __align__(16) bf16_t sP[4][32 * 72];

  const int krow = tid >> 3, kd = (tid & 7) * 8;   // K: 32 rows x 128B per pass
  const int vd = tid >> 2, pc = (tid & 3) * 8;     // V: 64 d-rows x 64B per pass
  const bf16_t* kb_g = base + 1024 + hoff;
  const float FNEG = -1e30f;

  const int np = (bx == 2) ? 4 : 2;
  for (int pass = 0; pass < np; ++pass) {
    // bx=0: 7,3   bx=1: 6,4   bx=2: 5,2,1,0   (heavy first; branchless)
    const int qt = (bx == 0) ? (7 - 4 * pass)
                 : (bx == 1) ? (6 - 2 * pass)
                             : ((pass == 0) ? 5 : 3 - pass);

    // Q fragments: 2 row-groups of 16, A-layout (m=lane15, k=quad*8+j)
    bf16x8 qa[2][2];
#pragma unroll
    for (int g = 0; g < 2; g++) {
      const int row = qt * 128 + wave * 32 + g * 16 + lane15;
      qa[g][0] = *(const bf16x8*)(base + (long)row * 2048 + hoff + quad * 8);
      qa[g][1] = *(const bf16x8*)(base + (long)row * 2048 + hoff + 32 + quad * 8);
    }

    float mrow[2][4], lrow[2][4];
    f32x4 o[2][4];
#pragma unroll
    for (int g = 0; g < 2; g++)
#pragma unroll
      for (int r = 0; r < 4; r++) { mrow[g][r] = FNEG; lrow[g][r] = 0.f; }
#pragma unroll
    for (int g = 0; g < 2; g++)
#pragma unroll
      for (int d4 = 0; d4 < 4; d4++) o[g][d4] = (f32x4){0.f, 0.f, 0.f, 0.f};

    // preload tile 0
    bf16x8 kA = *(const bf16x8*)(kb_g + (long)krow * 2048 + kd);
    bf16x8 kB = *(const bf16x8*)(kb_g + (long)(32 + krow) * 2048 + kd);
    bf16x8 vA = *(const bf16x8*)(vth + (long)vd * 1024 + pc);
    bf16x8 vB = *(const bf16x8*)(vth + (long)vd * 1024 + 32 + pc);

    const int qlo = qt * 128 + wave * 32;        // wave's lowest q-row
    const int ktiles = 2 * qt + 2;
    for (int kt = 0; kt < ktiles; kt++) {
      __syncthreads();  // prev tile's LDS reads done
      *(bf16x8*)&sK[krow * 72 + kd] = kA;
      *(bf16x8*)&sK[(krow + 32) * 72 + kd] = kB;
      *(bf16x8*)&sVt[vd * 72 + pc] = vA;
      *(bf16x8*)&sVt[vd * 72 + 32 + pc] = vB;
      __syncthreads();  // staging visible
      if (kt + 1 < ktiles) {  // prefetch next tile into regs (overlaps compute)
        const int nb = (kt + 1) * 64;
        kA = *(const bf16x8*)(kb_g + (long)(nb + krow) * 2048 + kd);
        kB = *(const bf16x8*)(kb_g + (long)(nb + 32 + krow) * 2048 + kd);
        vA = *(const bf16x8*)(vth + (long)vd * 1024 + nb + pc);
        vB = *(const bf16x8*)(vth + (long)vd * 1024 + nb + 32 + pc);
      }
      const int kbase = kt * 64;

      // S = Q K^T (K pre-scaled): per g, 4 key-groups x 2 k-chunks
      bf16x8 kb[4][2];
#pragma unroll
      for (int ns = 0; ns < 4; ns++) {
        kb[ns][0] = *(const bf16x8*)&sK[(ns * 16 + lane15) * 72 + quad * 8];
        kb[ns][1] = *(const bf16x8*)&sK[(ns * 16 + lane15) * 72 + 32 + quad * 8];
      }
      f32x4 s[2][4];
#pragma unroll
      for (int g = 0; g < 2; g++)
#pragma unroll
        for (int ns = 0; ns < 4; ns++) {
          f32x4 t = (f32x4){0.f, 0.f, 0.f, 0.f};
          t = MFMA16(qa[g][0], kb[ns][0], t);
          t = MFMA16(qa[g][1], kb[ns][1], t);
          s[g][ns] = t;
        }
      // causal mask (boundary tiles only; wave-uniform test)
      if (kbase + 63 > qlo) {
#pragma unroll
        for (int g = 0; g < 2; g++) {
          const int qc = qlo + g * 16 + quad * 4;
#pragma unroll
          for (int ns = 0; ns < 4; ns++) {
            const int kp = kbase + ns * 16 + lane15;
#pragma unroll
            for (int r = 0; r < 4; r++)
              if (kp > qc + r) s[g][ns][r] = FNEG;
          }
        }
      }
      // online softmax: tile max, defer-rescale if no new max
      float tm[2][4];
#pragma unroll
      for (int g = 0; g < 2; g++)
#pragma unroll
        for (int r = 0; r < 4; r++) {
          float t = fmaxf(fmaxf(s[g][0][r], s[g][1][r]),
                          fmaxf(s[g][2][r], s[g][3][r]));
          tm[g][r] = dpp_max16(t);
        }
      bool up = false;
#pragma unroll
      for (int g = 0; g < 2; g++)
#pragma unroll
        for (int r = 0; r < 4; r++) up = up || (tm[g][r] > mrow[g][r]);
      if (__any(up)) {
#pragma unroll
        for (int g = 0; g < 2; g++) {
          float alpha[4];
#pragma unroll
          for (int r = 0; r < 4; r++) {
            const float mn = fmaxf(mrow[g][r], tm[g][r]);
            alpha[r] = __expf(mrow[g][r] - mn);
            mrow[g][r] = mn;
          }
#pragma unroll
          for (int r = 0; r < 4; r++) lrow[g][r] *= alpha[r];
#pragma unroll
          for (int d4 = 0; d4 < 4; d4++)
#pragma unroll
            for (int r = 0; r < 4; r++) o[g][d4][r] *= alpha[r];
        }
      }
#pragma unroll
      for (int g = 0; g < 2; g++) {
#pragma unroll
        for (int ns = 0; ns < 4; ns++)
#pragma unroll
          for (int r = 0; r < 4; r++)
            s[g][ns][r] = __expf(s[g][ns][r] - mrow[g][r]);
#pragma unroll
        for (int r = 0; r < 4; r++) {
          float ts = (s[g][0][r] + s[g][1][r]) + (s[g][2][r] + s[g][3][r]);
          lrow[g][r] += dpp_sum16(ts);
        }
        // P: C-layout -> bf16 A-layout via per-wave LDS scratch
#pragma unroll
        for (int ns = 0; ns < 4; ns++)
#pragma unroll
          for (int r = 0; r < 4; r++)
            sP[wave][(g * 16 + quad * 4 + r) * 72 + ns * 16 + lane15] =
                (bf16_t)s[g][ns][r];
      }
      // PV
      bf16x8 vb[4][2];
#pragma unroll
      for (int d4 = 0; d4 < 4; d4++) {
        vb[d4][0] = *(const bf16x8*)&sVt[(d4 * 16 + lane15) * 72 + quad * 8];
        vb[d4][1] = *(const bf16x8*)&sVt[(d4 * 16 + lane15) * 72 + 32 + quad * 8];
      }
#pragma unroll
      for (int g = 0; g < 2; g++) {
        const bf16x8 pa0 = *(const bf16x8*)&sP[wave][(g * 16 + lane15) * 72 + quad * 8];
        const bf16x8 pa1 = *(const bf16x8*)&sP[wave][(g * 16 + lane15) * 72 + 32 + quad * 8];
#pragma unroll
        for (int d4 = 0; d4 < 4; d4++) {
          o[g][d4] = MFMA16(pa0, vb[d4][0], o[g][d4]);
          o[g][d4] = MFMA16(pa1, vb[d4][1], o[g][d4]);
        }
      }
    }

    // epilogue: normalize, bounce through sP (per-wave), vector store + perm
#pragma unroll
    for (int g = 0; g < 2; g++)
#pragma unroll
      for (int r = 0; r < 4; r++) {
        const float rinv = 1.f / fmaxf(lrow[g][r], 1e-20f);
#pragma unroll
        for (int d4 = 0; d4 < 4; d4++)
          sP[wave][(g * 16 + quad * 4 + r) * 72 + d4 * 16 + lane15] =
              (bf16_t)(o[g][d4][r] * rinv);
      }
#pragma unroll
    for (int g = 0; g < 2; g++) {
      const bf16x8 o0 = *(const bf16x8*)&sP[wave][(g * 16 + lane15) * 72 + quad * 16];
      const bf16x8 o1 = *(const bf16x8*)&sP[wave][(g * 16 + lane15) * 72 + quad * 16 + 8];
      const int tok = perm_t(qt * 128 + wave * 32 + g * 16 + lane15, dir);
      bf16_t* yr = yd + ((long)b * 1024 + tok) * 1024 + hoff + quad * 16;
      *(bf16x8*)yr = o0;
      *(bf16x8*)(yr + 8) = o1;
    }
  }
}

// ---------------------------------------------------------------------------
// RMSNorm over rows of 1024: v = P0 + P1 (+ P2 + P3) + x (split-K reduce +
// residual). p2/p3 may be null (2-way split fallback).
// ---------------------------------------------------------------------------
__global__ __launch_bounds__(256) void rmsnorm_k(const float* __restrict__ p0,
                                                 const float* __restrict__ p1,
                                                 const float* __restrict__ p2,
                                                 const float* __restrict__ p3,
                                                 const float* __restrict__ x,
                                                 const float* __restrict__ w,
                                                 float* __restrict__ out) {
  const int row = blockIdx.x, tid = threadIdx.x;
  const long off = (long)row * 1024;
  const float4 a = ((const float4*)(p0 + off))[tid];
  const float4 bq = ((const float4*)(p1 + off))[tid];
  const float4 c = ((const float4*)(x + off))[tid];
  float4 v;
  v.x = a.x + bq.x + c.x;
  v.y = a.y + bq.y + c.y;
  v.z = a.z + bq.z + c.z;
  v.w = a.w + bq.w + c.w;
  if (p2) {
    const float4 d = ((const float4*)(p2 + off))[tid];
    const float4 e = ((const float4*)(p3 + off))[tid];
    v.x += d.x + e.x;
    v.y += d.y + e.y;
    v.z += d.z + e.z;
    v.w += d.w + e.w;
  }
  float ss = v.x * v.x + v.y * v.y + v.z * v.z + v.w * v.w;
#pragma unroll
  for (int o2 = 32; o2 >= 1; o2 >>= 1) ss += __shfl_xor(ss, o2);
  __shared__ float wsum[4];
  if ((tid & 63) == 0) wsum[tid >> 6] = ss;
  __syncthreads();
  const float tot = wsum[0] + wsum[1] + wsum[2] + wsum[3];
  const float norm = rsqrtf(tot * (1.f / 1024.f) + 1e-6f);
  const float4 wv = ((const float4*)w)[tid];
  v.x = v.x * norm * wv.x;
  v.y = v.y * norm * wv.y;
  v.z = v.z * norm * wv.z;
  v.w = v.w * norm * wv.w;
  ((float4*)(out + off))[tid] = v;
}

// ---------------------------------------------------------------------------
extern "C" void kernel_launch(void* const* d_in, const int* in_sizes, int n_in,
                              void* d_out, int out_size, void* d_ws, size_t ws_size,
                              hipStream_t stream) {
  (void)in_sizes; (void)n_in; (void)out_size;
  const float* xf = (const float*)d_in[0];
  const float* wqkv_f[4] = {(const float*)d_in[1], (const float*)d_in[3],
                            (const float*)d_in[5], (const float*)d_in[7]};
  const float* wo_f[4] = {(const float*)d_in[2], (const float*)d_in[4],
                          (const float*)d_in[6], (const float*)d_in[8]};
  const float* wgate_f = (const float*)d_in[9];
  const float* bgate_f = (const float*)d_in[10];
  const float* wout_f = (const float*)d_in[11];
  const float* normw_f = (const float*)d_in[12];

  const long MB = 1l << 20;
  char* ws = (char*)d_ws;
  const dim3 blk(256);
  const dim3 blk2(512);
  const bool batched = ws_size >= (size_t)(168 * MB);
  const long sQK = 4096l * 2048;   // qk per-dir elems (16 MB)
  const long sVT = 4096l * 1024;   // vt per-dir elems (8 MB)
  const long sY  = 4096l * 1024;   // y per-dir elems (8 MB)

  if (batched) {
    bf16_t* x_c    = (bf16_t*)(ws);              // 8 MB   -> wout_c later
    bf16_t* wq_c   = (bf16_t*)(ws + 8 * MB);     // 24 MB
    bf16_t* wo_c   = (bf16_t*)(ws + 32 * MB);    // 8 MB
    bf16_t* qk     = (bf16_t*)(ws + 40 * MB);    // 64 MB (4 dirs, pos order)
    bf16_t* vt     = (bf16_t*)(ws + 104 * MB);   // 32 MB (4 dirs, [b][h][d][p])
    bf16_t* y      = (bf16_t*)(ws + 136 * MB);   // 32 MB -> gated
    bf16_t* concat = (bf16_t*)(ws + 40 * MB);    // 32 MB (phase 2, qk dirs 0-1 dead)
    bf16_t* wg_c   = (bf16_t*)(ws + 72 * MB);    // 32 MB (qk dirs 2-3 dead)
    bf16_t* wout_c = (bf16_t*)(ws);              // 8 MB (x dead)
    float*  part4  = (float*)(ws + 40 * MB);     // 64 MB (concat+wg dead after gate)
    bf16_t* gated  = y;

    {  // convert x, wqkv x4, wo x4
      CvtDesc cd;
      cd.src[0] = xf; cd.dst[0] = x_c; cd.n8[0] = 4194304 / 8;
      for (int d = 0; d < 4; d++) {
        cd.src[1 + d] = wqkv_f[d];
        cd.dst[1 + d] = wq_c + (long)d * 3145728;
        cd.n8[1 + d] = 3145728 / 8;
        cd.src[5 + d] = wo_f[d];
        cd.dst[5 + d] = wo_c + (long)d * 1048576;
        cd.n8[5 + d] = 1048576 / 8;
      }
      cvt9_k<<<dim3(2048, 9), blk, 0, stream>>>(cd);
    }
    {  // qkv GEMM (256^2 8-phase), 4 dirs: Q,K -> pos order; V -> vt transposed
      Ptr4 bq{{wq_c, wq_c + 3145728, wq_c + 2l * 3145728, wq_c + 3l * 3145728}};
      gemm_bt2<4><<<dim3(12, 16, 4), blk2, 0, stream>>>(
          x_c, 0, 1024, bq, 1024, qk, sQK, 2048, 1024, 0, nullptr, nullptr,
          vt, sVT, 0);
    }
    attn_k<<<dim3(3, 256), blk, 0, stream>>>(qk, sQK, vt, sVT, y, sY, 0);
    {  // convert wgate + wout (after attn: overlays qk/x space)
      CvtDesc cd;
      for (int s = 0; s < 9; s++) cd.n8[s] = 0;
      cd.src[0] = wgate_f; cd.dst[0] = wg_c; cd.n8[0] = 16777216 / 8;
      cd.src[1] = wout_f; cd.dst[1] = wout_c; cd.n8[1] = 4194304 / 8;
      cvt9_k<<<dim3(8192, 2), blk, 0, stream>>>(cd);
    }
    {  // out-proj, z-batched -> concat[:, z*1024:(z+1)*1024]  (256^2 8-phase)
      Ptr4 b4{{wo_c, wo_c + 1048576, wo_c + 2097152, wo_c + 3145728}};
      gemm_bt2<0><<<dim3(4, 16, 4), blk2, 0, stream>>>(
          y, sY, 1024, b4, 1024, concat, 1024, 4096, 1024, 0, nullptr, nullptr,
          nullptr, 0, 0);
    }
    {  // gated = sigmoid(concat@wg^T + b) * concat  (256^2 8-phase)
      Ptr4 b4{{wg_c, wg_c, wg_c, wg_c}};
      gemm_bt2<1><<<dim3(16, 16, 1), blk2, 0, stream>>>(
          concat, 0, 4096, b4, 4096, gated, 0, 4096, 4096, 0, bgate_f, concat,
          nullptr, 0, 0);
    }
    {  // split-K=4 w_out partials into part4 (concat/wg region, now dead)
      Ptr4 b4{{wout_c, wout_c, wout_c, wout_c}};
      gemm_bt2<3><<<dim3(4, 16, 4), blk2, 0, stream>>>(
          gated, 0, 4096, b4, 4096, part4, (long)4096 * 1024, 1024, 1024, 1024,
          nullptr, nullptr, nullptr, 0, 0);
    }
    rmsnorm_k<<<dim3(4096), blk, 0, stream>>>(
        part4, part4 + (long)4096 * 1024, part4 + 2l * 4096 * 1024,
        part4 + 3l * 4096 * 1024, xf, normw_f, (float*)d_out);
  } else {
    // fallback (96 MB): per-dir qkv+attn, legacy 128^2 GEMMs
    bf16_t* x_c    = (bf16_t*)(ws);              // 8 MB
    bf16_t* wq_c   = (bf16_t*)(ws + 8 * MB);     // 24 MB
    bf16_t* qk_d   = (bf16_t*)(ws + 32 * MB);    // 16 MB (per-dir)
    bf16_t* vt_d   = (bf16_t*)(ws + 48 * MB);    // 8 MB (per-dir)
    bf16_t* wo_c   = (bf16_t*)(ws + 56 * MB);    // 8 MB
    bf16_t* y      = (bf16_t*)(ws + 64 * MB);    // 32 MB -> gated
    bf16_t* concat = (bf16_t*)(ws);              // 32 MB (phase 2)
    bf16_t* wg_c   = (bf16_t*)(ws + 32 * MB);    // 32 MB (after out-proj)
    bf16_t* wout_c = (bf16_t*)(ws);              // 8 MB (after gate)
    float*  part   = (float*)(ws + 8 * MB);      // 32 MB
    bf16_t* gated  = y;

    {
      CvtDesc cd;
      cd.src[0] = xf; cd.dst[0] = x_c; cd.n8[0] = 4194304 / 8;
      for (int d = 0; d < 4; d++) {
        cd.src[1 + d] = wqkv_f[d];
        cd.dst[1 + d] = wq_c + (long)d * 3145728;
        cd.n8[1 + d] = 3145728 / 8;
        cd.src[5 + d] = wo_f[d];
        cd.dst[5 + d] = wo_c + (long)d * 1048576;
        cd.n8[5 + d] = 1048576 / 8;
      }
      cvt9_k<<<dim3(2048, 9), blk, 0, stream>>>(cd);
    }
    for (int d = 0; d < 4; d++) {
      const bf16_t* wq_d = wq_c + (long)d * 3145728;
      Ptr4 bq{{wq_d, wq_d, wq_d, wq_d}};
      gemm_bt<4><<<dim3(24, 32, 1), blk, 0, stream>>>(
          x_c, 0, 1024, bq, 1024, qk_d, 0, 2048, 1024, 0, nullptr, nullptr,
          vt_d, 0, d);
      attn_k<<<dim3(3, 64), blk, 0, stream>>>(qk_d, 0, vt_d, 0,
                                              y + (long)d * sY, 0, d);
    }
    {
      Ptr4 b4{{wo_c, wo_c + 1048576, wo_c + 2097152, wo_c + 3145728}};
      gemm_bt<0><<<dim3(8, 32, 4), blk, 0, stream>>>(
          y, sY, 1024, b4, 1024, concat, 1024, 4096, 1024, 0, nullptr, nullptr,
          nullptr, 0, 0);
    }
    {
      CvtDesc cd;
      for (int s = 0; s < 9; s++) cd.n8[s] = 0;
      cd.src[0] = wgate_f; cd.dst[0] = wg_c; cd.n8[0] = 16777216 / 8;
      cvt9_k<<<dim3(8192, 1), blk, 0, stream>>>(cd);
    }
    {
      Ptr4 b4{{wg_c, wg_c, wg_c, wg_c}};
      gemm_bt<1><<<dim3(32, 32, 1), blk, 0, stream>>>(
          concat, 0, 4096, b4, 4096, gated, 0, 4096, 4096, 0, bgate_f, concat,
          nullptr, 0, 0);
    }
    {
      CvtDesc cd;
      for (int s = 0; s < 9; s++) cd.n8[s] = 0;
      cd.src[0] = wout_f; cd.dst[0] = wout_c; cd.n8[0] = 4194304 / 8;
      cvt9_k<<<dim3(2048, 1), blk, 0, stream>>>(cd);
    }
    {
      Ptr4 b4{{wout_c, wout_c, wout_c, wout_c}};
      gemm_bt<3><<<dim3(8, 32, 2), blk, 0, stream>>>(
          gated, 0, 4096, b4, 4096, part, (long)4096 * 1024, 1024, 2048, 2048,
          nullptr, nullptr, nullptr, 0, 0);
    }
    rmsnorm_k<<<dim3(4096), blk, 0, stream>>>(part, part + (long)4096 * 1024,
                                              nullptr, nullptr,
                                              xf, normw_f, (float*)d_out);
  }
}